// Round 5
// baseline (2565.140 us; speedup 1.0000x reference)
//
#include <hip/hip_runtime.h>

// ---------------- problem constants ----------------
constexpr int Nres = 512;
constexpr int Cs   = 384;
constexpr int Cz   = 128;
constexpr int NH   = 12;
constexpr int HC   = 16;
constexpr int NPQ  = 4;
constexpr int NPV  = 8;
constexpr int NBLK = 8;
constexpr int PROJD = NH*HC + NH*2*HC + NH*NPQ*3 + NH*(NPQ+NPV)*3; // 1152
constexpr int CATD = NH*HC + NH*NPV*3 + NH*NPV + NH*Cz;            // 2112
constexpr int VHD  = NH * (HC + NPV*3);                             // 480
constexpr float W_L  = 0.57735026918962576f;  // sqrt(1/3)
constexpr float W_C2 = 0.11785113019775793f;  // sqrt(2/(9*PQ)) / 2

static inline int gdiv(int n, int b) { return (n + b - 1) / b; }

// ---------------- init ----------------
__global__ void k_init(const float* __restrict__ s_in, float* __restrict__ s_cur,
                       float* __restrict__ R, float* __restrict__ t) {
    int idx = blockIdx.x * blockDim.x + threadIdx.x;
    if (idx < Nres * Cs) s_cur[idx] = s_in[idx];
    if (idx < Nres * 9) {
        int e = idx % 9;
        R[idx] = (e == 0 || e == 4 || e == 8) ? 1.f : 0.f;
    }
    if (idx < Nres * 3) t[idx] = 0.f;
}

// concat projection weights into Wcat[384][1152]
__global__ void k_concatW(const float* __restrict__ w_q, const float* __restrict__ w_kv,
                          const float* __restrict__ w_qpts, const float* __restrict__ w_kvpts,
                          float* __restrict__ Wcat) {
    int idx = blockIdx.x * blockDim.x + threadIdx.x;
    if (idx >= Cs * PROJD) return;
    int k = idx / PROJD, n = idx - k * PROJD;
    float v;
    if      (n < 192) v = w_q[k * 192 + n];
    else if (n < 576) v = w_kv[k * 384 + (n - 192)];
    else if (n < 720) v = w_qpts[k * 144 + (n - 576)];
    else              v = w_kvpts[k * 432 + (n - 720)];
    Wcat[idx] = v;
}

// ---------------- split-K tiled GEMM ----------------
__global__ void __launch_bounds__(256)
k_gemm_sk(const float* __restrict__ A, const float* __restrict__ B,
          float* __restrict__ P, int M, int K, int N, int Kc) {
    __shared__ float As[32][66];
    __shared__ float Bs[32][64];
    const int tid = threadIdx.x;
    const int tx = tid & 15;
    const int ty = tid >> 4;
    const int m0 = blockIdx.y * 64;
    const int n0 = blockIdx.x * 64;
    const int kbeg = blockIdx.z * Kc;

    float acc[4][4] = {};

    for (int k0 = kbeg; k0 < kbeg + Kc; k0 += 32) {
#pragma unroll
        for (int l = 0; l < 8; l++) {
            int idx = tid + l * 256;
            int ak = idx & 31, am = idx >> 5;
            As[ak][am] = A[(size_t)(m0 + am) * K + k0 + ak];
        }
#pragma unroll
        for (int l = 0; l < 8; l++) {
            int idx = tid + l * 256;
            int bk = idx >> 6, bn = idx & 63;
            Bs[bk][bn] = B[(size_t)(k0 + bk) * N + n0 + bn];
        }
        __syncthreads();
#pragma unroll
        for (int kk = 0; kk < 32; kk++) {
            float2 a01 = *(const float2*)&As[kk][ty * 4];
            float2 a23 = *(const float2*)&As[kk][ty * 4 + 2];
            float4 b4  = *(const float4*)&Bs[kk][tx * 4];
            acc[0][0] += a01.x * b4.x; acc[0][1] += a01.x * b4.y;
            acc[0][2] += a01.x * b4.z; acc[0][3] += a01.x * b4.w;
            acc[1][0] += a01.y * b4.x; acc[1][1] += a01.y * b4.y;
            acc[1][2] += a01.y * b4.z; acc[1][3] += a01.y * b4.w;
            acc[2][0] += a23.x * b4.x; acc[2][1] += a23.x * b4.y;
            acc[2][2] += a23.x * b4.z; acc[2][3] += a23.x * b4.w;
            acc[3][0] += a23.y * b4.x; acc[3][1] += a23.y * b4.y;
            acc[3][2] += a23.y * b4.z; acc[3][3] += a23.y * b4.w;
        }
        __syncthreads();
    }
    float* Pp = P + (size_t)blockIdx.z * M * N;
#pragma unroll
    for (int r = 0; r < 4; r++) {
        float4 v = make_float4(acc[r][0], acc[r][1], acc[r][2], acc[r][3]);
        *(float4*)&Pp[(size_t)(m0 + ty * 4 + r) * N + n0 + tx * 4] = v;
    }
}

// reduce partials: mode 0 store, 1 relu-store, 2 accumulate into out
__global__ void k_reduce(const float* __restrict__ P, const float* __restrict__ bias,
                         float* __restrict__ out, int MN, int N, int nsplit, int mode) {
    int idx = blockIdx.x * blockDim.x + threadIdx.x;
    if (idx >= MN) return;
    float v = 0.f;
    for (int s = 0; s < nsplit; s++) v += P[(size_t)s * MN + idx];
    if (bias) v += bias[idx % N];
    if (mode == 1) v = fmaxf(v, 0.f);
    if (mode == 2) out[idx] += v;
    else           out[idx] = v;
}

// ---------------- b_hij (once) ----------------
__global__ void k_bproj(const float* __restrict__ z, const float* __restrict__ w_b,
                        float* __restrict__ b_hij) {
    __shared__ float zs[16][129];
    __shared__ float wbs[Cz * NH];
    const int tid = threadIdx.x;
    const int base = blockIdx.x * 16;
#pragma unroll
    for (int l = 0; l < 6; l++) {
        int idx = tid + l * 256;
        if (idx < Cz * NH) wbs[idx] = w_b[idx];
    }
#pragma unroll
    for (int l = 0; l < 8; l++) {
        int idx = tid + l * 256;
        int r = idx >> 7, c = idx & 127;
        zs[r][c] = z[(size_t)(base + r) * Cz + c];
    }
    __syncthreads();
    if (tid < 192) {
        int h = tid >> 4, r = tid & 15;
        float acc = 0.f;
        for (int c = 0; c < Cz; c++) acc += zs[r][c] * wbs[c * NH + h];
        int row = base + r;
        int i = row >> 9, j = row & 511;
        b_hij[((size_t)h * Nres + i) * Nres + j] = acc;
    }
}

// ---------------- prep: transform points, build staging (kT, kptsT, sqkT, vh) ----------------
__global__ void k_prep(const float* __restrict__ proj, const float* __restrict__ R,
                       const float* __restrict__ t,
                       float* __restrict__ qpts, float* __restrict__ sqq,
                       float* __restrict__ kT, float* __restrict__ kptsT,
                       float* __restrict__ sqkT, float* __restrict__ vh) {
    int idx = blockIdx.x * blockDim.x + threadIdx.x;
    if (idx >= NH * Nres) return;
    int h = idx / Nres, i = idx % Nres;
    float R_[9], t_[3];
#pragma unroll
    for (int e = 0; e < 9; e++) R_[e] = R[i * 9 + e];
#pragma unroll
    for (int e = 0; e < 3; e++) t_[e] = t[i * 3 + e];
    const float* prow = proj + (size_t)i * PROJD;
    float* vrow = vh + (size_t)i * VHD + h * 40;

    float sq = 0.f;
#pragma unroll
    for (int p = 0; p < NPQ; p++) {
        const float* src = prow + 576 + (h * NPQ + p) * 3;
        float y0 = src[0], y1 = src[1], y2 = src[2];
        float v0 = R_[0]*y0 + R_[1]*y1 + R_[2]*y2 + t_[0];
        float v1 = R_[3]*y0 + R_[4]*y1 + R_[5]*y2 + t_[1];
        float v2 = R_[6]*y0 + R_[7]*y1 + R_[8]*y2 + t_[2];
        float* dst = qpts + (size_t)i * (NH*NPQ*3) + h * NPQ*3 + p * 3;
        dst[0] = v0; dst[1] = v1; dst[2] = v2;
        sq += v0*v0 + v1*v1 + v2*v2;
    }
    sqq[i * NH + h] = sq;

    float sk = 0.f;
#pragma unroll
    for (int p = 0; p < NPQ + NPV; p++) {
        const float* src = prow + 720 + (h * (NPQ+NPV) + p) * 3;
        float y0 = src[0], y1 = src[1], y2 = src[2];
        float v0 = R_[0]*y0 + R_[1]*y1 + R_[2]*y2 + t_[0];
        float v1 = R_[3]*y0 + R_[4]*y1 + R_[5]*y2 + t_[1];
        float v2 = R_[6]*y0 + R_[7]*y1 + R_[8]*y2 + t_[2];
        if (p < NPQ) {
            kptsT[((size_t)h * (NPQ*3) + p*3 + 0) * Nres + i] = v0;
            kptsT[((size_t)h * (NPQ*3) + p*3 + 1) * Nres + i] = v1;
            kptsT[((size_t)h * (NPQ*3) + p*3 + 2) * Nres + i] = v2;
            sk += v0*v0 + v1*v1 + v2*v2;
        } else {
            int c0 = 16 + (p - NPQ) * 3;
            vrow[c0 + 0] = v0; vrow[c0 + 1] = v1; vrow[c0 + 2] = v2;
        }
    }
    sqkT[h * Nres + i] = sk;

#pragma unroll
    for (int c = 0; c < HC; c++) {
        kT[((size_t)h * HC + c) * Nres + i] = prow[192 + h * 2 * HC + c];
        vrow[c] = prow[192 + h * 2 * HC + HC + c];
    }
}

// ---------------- fused attention (conflict-free a_sT[j][13] layout) ----------------
__global__ void __launch_bounds__(256)
k_attn(const float* __restrict__ proj, const float* __restrict__ qpts,
       const float* __restrict__ sqq, const float* __restrict__ kT,
       const float* __restrict__ kptsT, const float* __restrict__ sqkT,
       const float* __restrict__ b_hij, const float* __restrict__ hw,
       const float* __restrict__ z, const float* __restrict__ vh,
       const float* __restrict__ R, const float* __restrict__ t,
       float* __restrict__ cat) {
    __shared__ __align__(16) float a_sT[512 * 13];  // probs; later reused as o_pair red buffer
    __shared__ float qs[NH * HC];
    __shared__ float qp[NH * 12];
    __shared__ float sqq_s[NH];
    __shared__ float gam[NH];
    __shared__ float optg_s[NH * NPV * 3];          // 288

    const int i = blockIdx.x;
    const int tid = threadIdx.x;
    const float* prow = proj + (size_t)i * PROJD;

    if (tid < NH * HC) qs[tid] = prow[tid];
    if (tid < NH * 12) qp[tid] = qpts[(size_t)i * 144 + tid];
    if (tid < NH) {
        sqq_s[tid] = sqq[i * NH + tid];
        gam[tid] = log1pf(__expf(hw[tid]));
    }
    __syncthreads();

    // ---- logits -> a_sT[j][h] ----
#pragma unroll 2
    for (int l = 0; l < 24; l++) {
        int idx = tid + l * 256;
        int h = idx >> 9, j = idx & 511;
        float sc = 0.f;
#pragma unroll
        for (int c = 0; c < HC; c++) sc += qs[h * 16 + c] * kT[((size_t)h * HC + c) * Nres + j];
        sc *= 0.25f;
        float cr = 0.f;
#pragma unroll
        for (int e = 0; e < 12; e++) cr += qp[h * 12 + e] * kptsT[((size_t)h * 12 + e) * Nres + j];
        float d2 = sqq_s[h] + sqkT[h * Nres + j] - 2.f * cr;
        a_sT[j * 13 + h] = W_L * (sc + b_hij[((size_t)h * Nres + i) * Nres + j] - gam[h] * W_C2 * d2);
    }
    __syncthreads();

    // ---- softmax per h-row: wave wv handles rows 3wv..3wv+2 ----
    {
        int wv = tid >> 6, ln = tid & 63;
        for (int r = wv * 3; r < wv * 3 + 3; r++) {
            float vals[8];
            float m = -1e30f;
#pragma unroll
            for (int jj = 0; jj < 8; jj++) { vals[jj] = a_sT[(ln + jj * 64) * 13 + r]; m = fmaxf(m, vals[jj]); }
#pragma unroll
            for (int off = 32; off > 0; off >>= 1) m = fmaxf(m, __shfl_xor(m, off));
            float sm = 0.f;
#pragma unroll
            for (int jj = 0; jj < 8; jj++) { vals[jj] = __expf(vals[jj] - m); sm += vals[jj]; }
#pragma unroll
            for (int off = 32; off > 0; off >>= 1) sm += __shfl_xor(sm, off);
            float inv = 1.f / sm;
#pragma unroll
            for (int jj = 0; jj < 8; jj++) a_sT[(ln + jj * 64) * 13 + r] = vals[jj] * inv;
        }
    }
    __syncthreads();

    float* crow = cat + (size_t)i * CATD;

    // ---- o + o_pt(global) : 480 outputs (idx = h*40 + c), all threads ----
    {
        const int i1 = tid;
        const int i2 = tid + 256;
        const bool has2 = (i2 < VHD);
        const int h1 = i1 / 40;
        const int h2 = has2 ? (i2 / 40) : 0;
        float acc0 = 0.f, acc1 = 0.f;
#pragma unroll 4
        for (int j = 0; j < Nres; j++) {
            const float* vrow = vh + (size_t)j * VHD;
            acc0 += a_sT[j * 13 + h1] * vrow[i1];
            if (has2) acc1 += a_sT[j * 13 + h2] * vrow[i2];
        }
        int c1 = i1 - h1 * 40;
        if (c1 < 16) crow[h1 * 16 + c1] = acc0; else optg_s[h1 * 24 + (c1 - 16)] = acc0;
        if (has2) {
            int c2 = i2 - h2 * 40;
            if (c2 < 16) crow[h2 * 16 + c2] = acc1; else optg_s[h2 * 24 + (c2 - 16)] = acc1;
        }
    }

    // ---- o_pair: 8 j-groups x 32 float4-lanes ----
    {
        const int grp = tid >> 5, zc4 = tid & 31;
        const float4* z4 = (const float4*)(z + (size_t)i * Nres * Cz);
        float4 accp[NH];
#pragma unroll
        for (int h = 0; h < NH; h++) accp[h] = make_float4(0.f, 0.f, 0.f, 0.f);
#pragma unroll 4
        for (int jj = 0; jj < 64; jj++) {
            int j = grp * 64 + jj;
            float4 zv = z4[j * 32 + zc4];
#pragma unroll
            for (int h = 0; h < NH; h++) {
                float a = a_sT[j * 13 + h];
                accp[h].x += a * zv.x; accp[h].y += a * zv.y;
                accp[h].z += a * zv.z; accp[h].w += a * zv.w;
            }
        }
        __syncthreads();   // a_sT now dead; optg_s fully written

        // pair-reduce groups (2w, 2w+1) via cross-half shuffle
#pragma unroll
        for (int h = 0; h < NH; h++) {
            accp[h].x += __shfl_xor(accp[h].x, 32);
            accp[h].y += __shfl_xor(accp[h].y, 32);
            accp[h].z += __shfl_xor(accp[h].z, 32);
            accp[h].w += __shfl_xor(accp[h].w, 32);
        }
        int wv = tid >> 6, ln = tid & 63;
        float4* red4 = (float4*)a_sT;   // reuse dead prob buffer (needs 4608 floats < 6656)
        if (wv >= 1 && ln < 32) {
#pragma unroll
            for (int h = 0; h < NH; h++) red4[(wv - 1) * 384 + h * 32 + ln] = accp[h];
        }

        // ---- o_pt local transform + norms (threads 128..223, overlapped) ----
        if (tid >= 128 && tid < 128 + NH * NPV) {
            int idx = tid - 128;
            int h = idx >> 3, p = idx & 7;
            float g0 = optg_s[h * 24 + p * 3 + 0];
            float g1 = optg_s[h * 24 + p * 3 + 1];
            float g2 = optg_s[h * 24 + p * 3 + 2];
            float d0 = g0 - t[i * 3 + 0], d1 = g1 - t[i * 3 + 1], d2v = g2 - t[i * 3 + 2];
            const float* Rn = R + i * 9;
            float l0 = Rn[0] * d0 + Rn[3] * d1 + Rn[6] * d2v;
            float l1 = Rn[1] * d0 + Rn[4] * d1 + Rn[7] * d2v;
            float l2 = Rn[2] * d0 + Rn[5] * d1 + Rn[8] * d2v;
            int hp = h * NPV + p;
            crow[192 + hp * 3 + 0] = l0;
            crow[192 + hp * 3 + 1] = l1;
            crow[192 + hp * 3 + 2] = l2;
            crow[480 + hp] = sqrtf(l0 * l0 + l1 * l1 + l2 * l2 + 1e-8f);
        }
        __syncthreads();

        if (wv == 0 && ln < 32) {
            float4* crow4 = (float4*)crow;
#pragma unroll
            for (int h = 0; h < NH; h++) {
                float4 v = accp[h];
#pragma unroll
                for (int w = 0; w < 3; w++) {
                    float4 r = red4[w * 384 + h * 32 + ln];
                    v.x += r.x; v.y += r.y; v.z += r.z; v.w += r.w;
                }
                crow4[144 + h * 32 + ln] = v;
            }
        }
    }
}

// ---------------- LayerNorm ----------------
__global__ void k_ln(float* __restrict__ s, const float* __restrict__ g,
                     const float* __restrict__ b) {
    __shared__ float red[512];
    int i = blockIdx.x, tid = threadIdx.x;
    float v = s[(size_t)i * Cs + tid];
    red[tid] = v;
    if (tid < 128) red[384 + tid] = 0.f;
    __syncthreads();
    for (int st = 256; st > 0; st >>= 1) { if (tid < st) red[tid] += red[tid + st]; __syncthreads(); }
    float mean = red[0] / Cs;
    __syncthreads();
    float d = v - mean;
    red[tid] = d * d;
    if (tid < 128) red[384 + tid] = 0.f;
    __syncthreads();
    for (int st = 256; st > 0; st >>= 1) { if (tid < st) red[tid] += red[tid + st]; __syncthreads(); }
    float var = red[0] / Cs;
    s[(size_t)i * Cs + tid] = d * rsqrtf(var + 1e-5f) * g[tid] + b[tid];
}

// ---------------- backbone update: one wave per residue ----------------
__global__ void k_bb(const float* __restrict__ s, const float* __restrict__ w_bb,
                     const float* __restrict__ b_bb, float* __restrict__ R, float* __restrict__ t) {
    int wv = threadIdx.x >> 6, lane = threadIdx.x & 63;
    int i = blockIdx.x * 4 + wv;
    const float* sr = s + (size_t)i * Cs;
    float u[6] = {};
#pragma unroll
    for (int k6 = 0; k6 < 6; k6++) {
        int k = lane + k6 * 64;
        float sv = sr[k];
#pragma unroll
        for (int d = 0; d < 6; d++) u[d] += sv * w_bb[k * 6 + d];
    }
#pragma unroll
    for (int off = 32; off > 0; off >>= 1)
#pragma unroll
        for (int d = 0; d < 6; d++) u[d] += __shfl_down(u[d], off);
    if (lane == 0) {
#pragma unroll
        for (int d = 0; d < 6; d++) u[d] += b_bb[d];
        float qb = u[0], qc = u[1], qd = u[2];
        float inv = rsqrtf(1.f + qb*qb + qc*qc + qd*qd);
        float w = inv, x = qb * inv, y = qc * inv, zq = qd * inv;
        float Ru[9] = {
            1.f - 2.f*(y*y + zq*zq), 2.f*(x*y - w*zq),       2.f*(x*zq + w*y),
            2.f*(x*y + w*zq),        1.f - 2.f*(x*x + zq*zq), 2.f*(y*zq - w*x),
            2.f*(x*zq - w*y),        2.f*(y*zq + w*x),        1.f - 2.f*(x*x + y*y)
        };
        float Ro[9];
#pragma unroll
        for (int e = 0; e < 9; e++) Ro[e] = R[i * 9 + e];
        float tu0 = u[3], tu1 = u[4], tu2 = u[5];
        t[i*3+0] += Ro[0]*tu0 + Ro[1]*tu1 + Ro[2]*tu2;
        t[i*3+1] += Ro[3]*tu0 + Ro[4]*tu1 + Ro[5]*tu2;
        t[i*3+2] += Ro[6]*tu0 + Ro[7]*tu1 + Ro[8]*tu2;
#pragma unroll
        for (int r = 0; r < 3; r++)
#pragma unroll
            for (int c = 0; c < 3; c++)
                R[i*9 + r*3 + c] = Ro[r*3+0]*Ru[0*3+c] + Ro[r*3+1]*Ru[1*3+c] + Ro[r*3+2]*Ru[2*3+c];
    }
}

// ---------------- final pack ----------------
__global__ void k_final(const float* __restrict__ s, const float* __restrict__ t,
                        float* __restrict__ out) {
    int idx = blockIdx.x * blockDim.x + threadIdx.x;
    if (idx >= Nres * (Cs + 3)) return;
    int i = idx / (Cs + 3), c = idx - i * (Cs + 3);
    out[idx] = (c < Cs) ? s[(size_t)i * Cs + c] : t[i * 3 + (c - Cs)];
}

// ---------------- launch ----------------
extern "C" void kernel_launch(void* const* d_in, const int* in_sizes, int n_in,
                              void* d_out, int out_size, void* d_ws, size_t ws_size,
                              hipStream_t stream) {
    const float* s_in    = (const float*)d_in[0];
    const float* z       = (const float*)d_in[1];
    const float* w_q     = (const float*)d_in[2];
    const float* w_kv    = (const float*)d_in[3];
    const float* w_qpts  = (const float*)d_in[4];
    const float* w_kvpts = (const float*)d_in[5];
    const float* w_b     = (const float*)d_in[6];
    const float* hw      = (const float*)d_in[7];
    const float* w_out   = (const float*)d_in[8];
    const float* b_out   = (const float*)d_in[9];
    const float* ln1_g   = (const float*)d_in[10];
    const float* ln1_b   = (const float*)d_in[11];
    const float* w_t1    = (const float*)d_in[12];
    const float* w_t2    = (const float*)d_in[13];
    const float* w_t3    = (const float*)d_in[14];
    const float* ln2_g   = (const float*)d_in[15];
    const float* ln2_b   = (const float*)d_in[16];
    const float* w_bb    = (const float*)d_in[17];
    const float* b_bb    = (const float*)d_in[18];
    float* out = (float*)d_out;

    float* ws = (float*)d_ws;
    size_t off = 0;
    float* s_cur = ws + off; off += (size_t)Nres * Cs;
    float* b_hij = ws + off; off += (size_t)NH * Nres * Nres;
    float* proj  = ws + off; off += (size_t)Nres * PROJD;
    float* Wcat  = ws + off; off += (size_t)Cs * PROJD;
    float* qpts  = ws + off; off += (size_t)Nres * NH * NPQ * 3;
    float* sqq   = ws + off; off += (size_t)Nres * NH;
    float* kT    = ws + off; off += (size_t)NH * HC * Nres;
    float* kptsT = ws + off; off += (size_t)NH * NPQ * 3 * Nres;
    float* sqkT  = ws + off; off += (size_t)NH * Nres;
    float* vh    = ws + off; off += (size_t)Nres * VHD;
    float* catb  = ws + off; off += (size_t)Nres * CATD;
    float* Rbuf  = ws + off; off += (size_t)Nres * 9;
    float* tbuf  = ws + off; off += (size_t)Nres * 3;
    float* h1    = ws + off; off += (size_t)Nres * Cs;
    float* h2    = ws + off; off += (size_t)Nres * Cs;
    float* Pslab = ws + off; off += (size_t)11 * Nres * Cs;

    const int MNp = Nres * PROJD;
    const int MNs = Nres * Cs;

    k_init<<<gdiv(Nres*Cs, 256), 256, 0, stream>>>(s_in, s_cur, Rbuf, tbuf);
    k_concatW<<<gdiv(Cs*PROJD, 256), 256, 0, stream>>>(w_q, w_kv, w_qpts, w_kvpts, Wcat);
    k_bproj<<<Nres*Nres/16, 256, 0, stream>>>(z, w_b, b_hij);

    for (int it = 0; it < NBLK; it++) {
        // fused projections: proj = s_cur @ Wcat (512 x 384 x 1152), split-K=2
        k_gemm_sk<<<dim3(PROJD/64, Nres/64, 2), 256, 0, stream>>>(s_cur, Wcat, Pslab, Nres, Cs, PROJD, 192);
        k_reduce<<<gdiv(MNp, 256), 256, 0, stream>>>(Pslab, nullptr, proj, MNp, PROJD, 2, 0);
        // point transforms + staging
        k_prep<<<gdiv(NH*Nres, 256), 256, 0, stream>>>(proj, Rbuf, tbuf, qpts, sqq, kT, kptsT, sqkT, vh);
        // fused attention -> cat
        k_attn<<<Nres, 256, 0, stream>>>(proj, qpts, sqq, kT, kptsT, sqkT, b_hij, hw, z, vh, Rbuf, tbuf, catb);
        // s += cat @ w_out + b_out (512 x 2112 x 384), split-K=11
        k_gemm_sk<<<dim3(Cs/64, Nres/64, 11), 256, 0, stream>>>(catb, w_out, Pslab, Nres, CATD, Cs, 192);
        k_reduce<<<gdiv(MNs, 256), 256, 0, stream>>>(Pslab, b_out, s_cur, MNs, Cs, 11, 2);
        k_ln<<<Nres, Cs, 0, stream>>>(s_cur, ln1_g, ln1_b);
        // transition (512 x 384 x 384), split-K=6
        k_gemm_sk<<<dim3(Cs/64, Nres/64, 6), 256, 0, stream>>>(s_cur, w_t1, Pslab, Nres, Cs, Cs, 64);
        k_reduce<<<gdiv(MNs, 256), 256, 0, stream>>>(Pslab, nullptr, h1, MNs, Cs, 6, 1);
        k_gemm_sk<<<dim3(Cs/64, Nres/64, 6), 256, 0, stream>>>(h1, w_t2, Pslab, Nres, Cs, Cs, 64);
        k_reduce<<<gdiv(MNs, 256), 256, 0, stream>>>(Pslab, nullptr, h2, MNs, Cs, 6, 1);
        k_gemm_sk<<<dim3(Cs/64, Nres/64, 6), 256, 0, stream>>>(h2, w_t3, Pslab, Nres, Cs, Cs, 64);
        k_reduce<<<gdiv(MNs, 256), 256, 0, stream>>>(Pslab, nullptr, s_cur, MNs, Cs, 6, 2);
        k_ln<<<Nres, Cs, 0, stream>>>(s_cur, ln2_g, ln2_b);
        // backbone update
        k_bb<<<Nres/4, 256, 0, stream>>>(s_cur, w_bb, b_bb, Rbuf, tbuf);
    }

    k_final<<<gdiv(Nres*(Cs+3), 256), 256, 0, stream>>>(s_cur, tbuf, out);
}

// Round 6
// 2211.574 us; speedup vs baseline: 1.1599x; 1.1599x over previous
//
#include <hip/hip_runtime.h>

// ---------------- problem constants ----------------
constexpr int Nres = 512;
constexpr int Cs   = 384;
constexpr int Cz   = 128;
constexpr int NH   = 12;
constexpr int HC   = 16;
constexpr int NPQ  = 4;
constexpr int NPV  = 8;
constexpr int NBLK = 8;
constexpr int PROJD = NH*HC + NH*2*HC + NH*NPQ*3 + NH*(NPQ+NPV)*3; // 1152
constexpr int CATD = NH*HC + NH*NPV*3 + NH*NPV + NH*Cz;            // 2112
constexpr int VHD  = NH * (HC + NPV*3);                             // 480
constexpr float W_L  = 0.57735026918962576f;  // sqrt(1/3)
constexpr float W_C2 = 0.11785113019775793f;  // sqrt(2/(9*PQ)) / 2

static inline int gdiv(int n, int b) { return (n + b - 1) / b; }

// ---------------- init ----------------
__global__ void k_init(const float* __restrict__ s_in, float* __restrict__ s_cur,
                       float* __restrict__ R, float* __restrict__ t) {
    int idx = blockIdx.x * blockDim.x + threadIdx.x;
    if (idx < Nres * Cs) s_cur[idx] = s_in[idx];
    if (idx < Nres * 9) {
        int e = idx % 9;
        R[idx] = (e == 0 || e == 4 || e == 8) ? 1.f : 0.f;
    }
    if (idx < Nres * 3) t[idx] = 0.f;
}

// concat projection weights into Wcat[384][1152]
__global__ void k_concatW(const float* __restrict__ w_q, const float* __restrict__ w_kv,
                          const float* __restrict__ w_qpts, const float* __restrict__ w_kvpts,
                          float* __restrict__ Wcat) {
    int idx = blockIdx.x * blockDim.x + threadIdx.x;
    if (idx >= Cs * PROJD) return;
    int k = idx / PROJD, n = idx - k * PROJD;
    float v;
    if      (n < 192) v = w_q[k * 192 + n];
    else if (n < 576) v = w_kv[k * 384 + (n - 192)];
    else if (n < 720) v = w_qpts[k * 144 + (n - 576)];
    else              v = w_kvpts[k * 432 + (n - 720)];
    Wcat[idx] = v;
}

// ---------------- split-K tiled GEMM ----------------
__global__ void __launch_bounds__(256)
k_gemm_sk(const float* __restrict__ A, const float* __restrict__ B,
          float* __restrict__ P, int M, int K, int N, int Kc) {
    __shared__ float As[32][66];
    __shared__ float Bs[32][64];
    const int tid = threadIdx.x;
    const int tx = tid & 15;
    const int ty = tid >> 4;
    const int m0 = blockIdx.y * 64;
    const int n0 = blockIdx.x * 64;
    const int kbeg = blockIdx.z * Kc;

    float acc[4][4] = {};

    for (int k0 = kbeg; k0 < kbeg + Kc; k0 += 32) {
#pragma unroll
        for (int l = 0; l < 8; l++) {
            int idx = tid + l * 256;
            int ak = idx & 31, am = idx >> 5;
            As[ak][am] = A[(size_t)(m0 + am) * K + k0 + ak];
        }
#pragma unroll
        for (int l = 0; l < 8; l++) {
            int idx = tid + l * 256;
            int bk = idx >> 6, bn = idx & 63;
            Bs[bk][bn] = B[(size_t)(k0 + bk) * N + n0 + bn];
        }
        __syncthreads();
#pragma unroll
        for (int kk = 0; kk < 32; kk++) {
            float2 a01 = *(const float2*)&As[kk][ty * 4];
            float2 a23 = *(const float2*)&As[kk][ty * 4 + 2];
            float4 b4  = *(const float4*)&Bs[kk][tx * 4];
            acc[0][0] += a01.x * b4.x; acc[0][1] += a01.x * b4.y;
            acc[0][2] += a01.x * b4.z; acc[0][3] += a01.x * b4.w;
            acc[1][0] += a01.y * b4.x; acc[1][1] += a01.y * b4.y;
            acc[1][2] += a01.y * b4.z; acc[1][3] += a01.y * b4.w;
            acc[2][0] += a23.x * b4.x; acc[2][1] += a23.x * b4.y;
            acc[2][2] += a23.x * b4.z; acc[2][3] += a23.x * b4.w;
            acc[3][0] += a23.y * b4.x; acc[3][1] += a23.y * b4.y;
            acc[3][2] += a23.y * b4.z; acc[3][3] += a23.y * b4.w;
        }
        __syncthreads();
    }
    float* Pp = P + (size_t)blockIdx.z * M * N;
#pragma unroll
    for (int r = 0; r < 4; r++) {
        float4 v = make_float4(acc[r][0], acc[r][1], acc[r][2], acc[r][3]);
        *(float4*)&Pp[(size_t)(m0 + ty * 4 + r) * N + n0 + tx * 4] = v;
    }
}

// reduce partials: mode 0 store, 1 relu-store, 2 accumulate into out
__global__ void k_reduce(const float* __restrict__ P, const float* __restrict__ bias,
                         float* __restrict__ out, int MN, int N, int nsplit, int mode) {
    int idx = blockIdx.x * blockDim.x + threadIdx.x;
    if (idx >= MN) return;
    float v = 0.f;
    for (int s = 0; s < nsplit; s++) v += P[(size_t)s * MN + idx];
    if (bias) v += bias[idx % N];
    if (mode == 1) v = fmaxf(v, 0.f);
    if (mode == 2) out[idx] += v;
    else           out[idx] = v;
}

// ---------------- b_hij (once) ----------------
__global__ void k_bproj(const float* __restrict__ z, const float* __restrict__ w_b,
                        float* __restrict__ b_hij) {
    __shared__ float zs[16][129];
    __shared__ float wbs[Cz * NH];
    const int tid = threadIdx.x;
    const int base = blockIdx.x * 16;
#pragma unroll
    for (int l = 0; l < 6; l++) {
        int idx = tid + l * 256;
        if (idx < Cz * NH) wbs[idx] = w_b[idx];
    }
#pragma unroll
    for (int l = 0; l < 8; l++) {
        int idx = tid + l * 256;
        int r = idx >> 7, c = idx & 127;
        zs[r][c] = z[(size_t)(base + r) * Cz + c];
    }
    __syncthreads();
    if (tid < 192) {
        int h = tid >> 4, r = tid & 15;
        float acc = 0.f;
        for (int c = 0; c < Cz; c++) acc += zs[r][c] * wbs[c * NH + h];
        int row = base + r;
        int i = row >> 9, j = row & 511;
        b_hij[((size_t)h * Nres + i) * Nres + j] = acc;
    }
}

// ---------------- prep: transform points, build staging (kT, kptsT, sqkT, vh) ----------------
__global__ void k_prep(const float* __restrict__ proj, const float* __restrict__ R,
                       const float* __restrict__ t,
                       float* __restrict__ qpts, float* __restrict__ sqq,
                       float* __restrict__ kT, float* __restrict__ kptsT,
                       float* __restrict__ sqkT, float* __restrict__ vh) {
    int idx = blockIdx.x * blockDim.x + threadIdx.x;
    if (idx >= NH * Nres) return;
    int h = idx / Nres, i = idx % Nres;
    float R_[9], t_[3];
#pragma unroll
    for (int e = 0; e < 9; e++) R_[e] = R[i * 9 + e];
#pragma unroll
    for (int e = 0; e < 3; e++) t_[e] = t[i * 3 + e];
    const float* prow = proj + (size_t)i * PROJD;
    float* vrow = vh + (size_t)i * VHD + h * 40;

    float sq = 0.f;
#pragma unroll
    for (int p = 0; p < NPQ; p++) {
        const float* src = prow + 576 + (h * NPQ + p) * 3;
        float y0 = src[0], y1 = src[1], y2 = src[2];
        float v0 = R_[0]*y0 + R_[1]*y1 + R_[2]*y2 + t_[0];
        float v1 = R_[3]*y0 + R_[4]*y1 + R_[5]*y2 + t_[1];
        float v2 = R_[6]*y0 + R_[7]*y1 + R_[8]*y2 + t_[2];
        float* dst = qpts + (size_t)i * (NH*NPQ*3) + h * NPQ*3 + p * 3;
        dst[0] = v0; dst[1] = v1; dst[2] = v2;
        sq += v0*v0 + v1*v1 + v2*v2;
    }
    sqq[i * NH + h] = sq;

    float sk = 0.f;
#pragma unroll
    for (int p = 0; p < NPQ + NPV; p++) {
        const float* src = prow + 720 + (h * (NPQ+NPV) + p) * 3;
        float y0 = src[0], y1 = src[1], y2 = src[2];
        float v0 = R_[0]*y0 + R_[1]*y1 + R_[2]*y2 + t_[0];
        float v1 = R_[3]*y0 + R_[4]*y1 + R_[5]*y2 + t_[1];
        float v2 = R_[6]*y0 + R_[7]*y1 + R_[8]*y2 + t_[2];
        if (p < NPQ) {
            kptsT[((size_t)h * (NPQ*3) + p*3 + 0) * Nres + i] = v0;
            kptsT[((size_t)h * (NPQ*3) + p*3 + 1) * Nres + i] = v1;
            kptsT[((size_t)h * (NPQ*3) + p*3 + 2) * Nres + i] = v2;
            sk += v0*v0 + v1*v1 + v2*v2;
        } else {
            int c0 = 16 + (p - NPQ) * 3;
            vrow[c0 + 0] = v0; vrow[c0 + 1] = v1; vrow[c0 + 2] = v2;
        }
    }
    sqkT[h * Nres + i] = sk;

#pragma unroll
    for (int c = 0; c < HC; c++) {
        kT[((size_t)h * HC + c) * Nres + i] = prow[192 + h * 2 * HC + c];
        vrow[c] = prow[192 + h * 2 * HC + HC + c];
    }
}

// ---------------- fused attention, head-group split ----------------
// grid (Nres, 3): block (i, hg) handles heads hg*4 .. hg*4+3
__global__ void __launch_bounds__(256)
k_attn(const float* __restrict__ proj, const float* __restrict__ qpts,
       const float* __restrict__ sqq, const float* __restrict__ kT,
       const float* __restrict__ kptsT, const float* __restrict__ sqkT,
       const float* __restrict__ b_hij, const float* __restrict__ hw,
       const float* __restrict__ z, const float* __restrict__ vh,
       const float* __restrict__ R, const float* __restrict__ t,
       float* __restrict__ cat) {
    __shared__ float a_sT[512 * 5];      // probs [j][h], stride 5 (coprime 32); reused as red buf
    __shared__ float qs[4 * HC];
    __shared__ float qp[4 * 12];
    __shared__ float sqq_s[4];
    __shared__ float gam[4];
    __shared__ float optg_s[4 * NPV * 3];  // 96

    const int i  = blockIdx.x;
    const int hg = blockIdx.y;           // head group
    const int tid = threadIdx.x;

    if (tid < 64) qs[tid] = proj[(size_t)i * PROJD + hg * 64 + tid];
    if (tid < 48) qp[tid] = qpts[(size_t)i * 144 + hg * 48 + tid];
    if (tid < 4) {
        sqq_s[tid] = sqq[i * NH + hg * 4 + tid];
        gam[tid] = log1pf(__expf(hw[hg * 4 + tid]));
    }
    __syncthreads();

    // ---- logits: 4 heads x 512 j ----
#pragma unroll
    for (int l = 0; l < 8; l++) {
        int idx = tid + l * 256;
        int h = idx >> 9, j = idx & 511;    // h in [0,4)
        int hglob = hg * 4 + h;
        float sc = 0.f;
#pragma unroll
        for (int c = 0; c < HC; c++) sc += qs[h * 16 + c] * kT[((size_t)hglob * HC + c) * Nres + j];
        sc *= 0.25f;
        float cr = 0.f;
#pragma unroll
        for (int e = 0; e < 12; e++) cr += qp[h * 12 + e] * kptsT[((size_t)hglob * 12 + e) * Nres + j];
        float d2 = sqq_s[h] + sqkT[hglob * Nres + j] - 2.f * cr;
        a_sT[j * 5 + h] = W_L * (sc + b_hij[((size_t)hglob * Nres + i) * Nres + j] - gam[h] * W_C2 * d2);
    }
    __syncthreads();

    // ---- softmax: wave wv handles row wv ----
    {
        int wv = tid >> 6, ln = tid & 63;
        float vals[8];
        float m = -1e30f;
#pragma unroll
        for (int jj = 0; jj < 8; jj++) { vals[jj] = a_sT[(ln + jj * 64) * 5 + wv]; m = fmaxf(m, vals[jj]); }
#pragma unroll
        for (int off = 32; off > 0; off >>= 1) m = fmaxf(m, __shfl_xor(m, off));
        float sm = 0.f;
#pragma unroll
        for (int jj = 0; jj < 8; jj++) { vals[jj] = __expf(vals[jj] - m); sm += vals[jj]; }
#pragma unroll
        for (int off = 32; off > 0; off >>= 1) sm += __shfl_xor(sm, off);
        float inv = 1.f / sm;
#pragma unroll
        for (int jj = 0; jj < 8; jj++) a_sT[(ln + jj * 64) * 5 + wv] = vals[jj] * inv;
    }
    __syncthreads();

    float* crow = cat + (size_t)i * CATD;

    // ---- o + o_pt(global): 160 outputs (4 heads x 40) ----
    if (tid < 160) {
        int h = tid / 40;                 // local head
        int c = tid - h * 40;             // 0..39
        int hglob = hg * 4 + h;
        float acc = 0.f;
        const float* vcol = vh + hglob * 40 + c;
#pragma unroll 4
        for (int j = 0; j < Nres; j++)
            acc += a_sT[j * 5 + h] * vcol[(size_t)j * VHD];
        if (c < 16) crow[hglob * 16 + c] = acc;
        else        optg_s[h * 24 + (c - 16)] = acc;
    }

    // ---- o_pair: 4 heads, halves over j ----
    {
        const int zc = tid & 127, half = tid >> 7;
        float accp[4] = {};
        const float* zrow = z + ((size_t)i * Nres + half * 256) * Cz + zc;
#pragma unroll 4
        for (int j = 0; j < 256; j++) {
            float zv = zrow[(size_t)j * Cz];
            int jj = half * 256 + j;
#pragma unroll
            for (int h = 0; h < 4; h++) accp[h] += a_sT[jj * 5 + h] * zv;
        }
        __syncthreads();   // all loops done; a_sT probs now dead

        if (half == 1) {
#pragma unroll
            for (int h = 0; h < 4; h++) a_sT[h * 128 + zc] = accp[h];
        }
        // o_pt local transform + norms (threads 224..255, wave 3, after its red write)
        if (tid >= 224) {
            int idx = tid - 224;          // 0..31
            int h = idx >> 3, p = idx & 7;
            int hglob = hg * 4 + h;
            float g0 = optg_s[h * 24 + p * 3 + 0];
            float g1 = optg_s[h * 24 + p * 3 + 1];
            float g2 = optg_s[h * 24 + p * 3 + 2];
            float d0 = g0 - t[i * 3 + 0], d1 = g1 - t[i * 3 + 1], d2v = g2 - t[i * 3 + 2];
            const float* Rn = R + i * 9;
            float l0 = Rn[0] * d0 + Rn[3] * d1 + Rn[6] * d2v;
            float l1 = Rn[1] * d0 + Rn[4] * d1 + Rn[7] * d2v;
            float l2 = Rn[2] * d0 + Rn[5] * d1 + Rn[8] * d2v;
            int hp = hglob * NPV + p;
            crow[192 + hp * 3 + 0] = l0;
            crow[192 + hp * 3 + 1] = l1;
            crow[192 + hp * 3 + 2] = l2;
            crow[480 + hp] = sqrtf(l0 * l0 + l1 * l1 + l2 * l2 + 1e-8f);
        }
        __syncthreads();

        if (half == 0) {
#pragma unroll
            for (int h = 0; h < 4; h++)
                crow[576 + (hg * 4 + h) * Cz + zc] = accp[h] + a_sT[h * 128 + zc];
        }
    }
}

// ---------------- LayerNorm ----------------
__global__ void k_ln(float* __restrict__ s, const float* __restrict__ g,
                     const float* __restrict__ b) {
    __shared__ float red[512];
    int i = blockIdx.x, tid = threadIdx.x;
    float v = s[(size_t)i * Cs + tid];
    red[tid] = v;
    if (tid < 128) red[384 + tid] = 0.f;
    __syncthreads();
    for (int st = 256; st > 0; st >>= 1) { if (tid < st) red[tid] += red[tid + st]; __syncthreads(); }
    float mean = red[0] / Cs;
    __syncthreads();
    float d = v - mean;
    red[tid] = d * d;
    if (tid < 128) red[384 + tid] = 0.f;
    __syncthreads();
    for (int st = 256; st > 0; st >>= 1) { if (tid < st) red[tid] += red[tid + st]; __syncthreads(); }
    float var = red[0] / Cs;
    s[(size_t)i * Cs + tid] = d * rsqrtf(var + 1e-5f) * g[tid] + b[tid];
}

// ---------------- backbone update: one wave per residue ----------------
__global__ void k_bb(const float* __restrict__ s, const float* __restrict__ w_bb,
                     const float* __restrict__ b_bb, float* __restrict__ R, float* __restrict__ t) {
    int wv = threadIdx.x >> 6, lane = threadIdx.x & 63;
    int i = blockIdx.x * 4 + wv;
    const float* sr = s + (size_t)i * Cs;
    float u[6] = {};
#pragma unroll
    for (int k6 = 0; k6 < 6; k6++) {
        int k = lane + k6 * 64;
        float sv = sr[k];
#pragma unroll
        for (int d = 0; d < 6; d++) u[d] += sv * w_bb[k * 6 + d];
    }
#pragma unroll
    for (int off = 32; off > 0; off >>= 1)
#pragma unroll
        for (int d = 0; d < 6; d++) u[d] += __shfl_down(u[d], off);
    if (lane == 0) {
#pragma unroll
        for (int d = 0; d < 6; d++) u[d] += b_bb[d];
        float qb = u[0], qc = u[1], qd = u[2];
        float inv = rsqrtf(1.f + qb*qb + qc*qc + qd*qd);
        float w = inv, x = qb * inv, y = qc * inv, zq = qd * inv;
        float Ru[9] = {
            1.f - 2.f*(y*y + zq*zq), 2.f*(x*y - w*zq),       2.f*(x*zq + w*y),
            2.f*(x*y + w*zq),        1.f - 2.f*(x*x + zq*zq), 2.f*(y*zq - w*x),
            2.f*(x*zq - w*y),        2.f*(y*zq + w*x),        1.f - 2.f*(x*x + y*y)
        };
        float Ro[9];
#pragma unroll
        for (int e = 0; e < 9; e++) Ro[e] = R[i * 9 + e];
        float tu0 = u[3], tu1 = u[4], tu2 = u[5];
        t[i*3+0] += Ro[0]*tu0 + Ro[1]*tu1 + Ro[2]*tu2;
        t[i*3+1] += Ro[3]*tu0 + Ro[4]*tu1 + Ro[5]*tu2;
        t[i*3+2] += Ro[6]*tu0 + Ro[7]*tu1 + Ro[8]*tu2;
#pragma unroll
        for (int r = 0; r < 3; r++)
#pragma unroll
            for (int c = 0; c < 3; c++)
                R[i*9 + r*3 + c] = Ro[r*3+0]*Ru[0*3+c] + Ro[r*3+1]*Ru[1*3+c] + Ro[r*3+2]*Ru[2*3+c];
    }
}

// ---------------- final pack ----------------
__global__ void k_final(const float* __restrict__ s, const float* __restrict__ t,
                        float* __restrict__ out) {
    int idx = blockIdx.x * blockDim.x + threadIdx.x;
    if (idx >= Nres * (Cs + 3)) return;
    int i = idx / (Cs + 3), c = idx - i * (Cs + 3);
    out[idx] = (c < Cs) ? s[(size_t)i * Cs + c] : t[i * 3 + (c - Cs)];
}

// ---------------- launch ----------------
extern "C" void kernel_launch(void* const* d_in, const int* in_sizes, int n_in,
                              void* d_out, int out_size, void* d_ws, size_t ws_size,
                              hipStream_t stream) {
    const float* s_in    = (const float*)d_in[0];
    const float* z       = (const float*)d_in[1];
    const float* w_q     = (const float*)d_in[2];
    const float* w_kv    = (const float*)d_in[3];
    const float* w_qpts  = (const float*)d_in[4];
    const float* w_kvpts = (const float*)d_in[5];
    const float* w_b     = (const float*)d_in[6];
    const float* hw      = (const float*)d_in[7];
    const float* w_out   = (const float*)d_in[8];
    const float* b_out   = (const float*)d_in[9];
    const float* ln1_g   = (const float*)d_in[10];
    const float* ln1_b   = (const float*)d_in[11];
    const float* w_t1    = (const float*)d_in[12];
    const float* w_t2    = (const float*)d_in[13];
    const float* w_t3    = (const float*)d_in[14];
    const float* ln2_g   = (const float*)d_in[15];
    const float* ln2_b   = (const float*)d_in[16];
    const float* w_bb    = (const float*)d_in[17];
    const float* b_bb    = (const float*)d_in[18];
    float* out = (float*)d_out;

    float* ws = (float*)d_ws;
    size_t off = 0;
    float* s_cur = ws + off; off += (size_t)Nres * Cs;
    float* b_hij = ws + off; off += (size_t)NH * Nres * Nres;
    float* proj  = ws + off; off += (size_t)Nres * PROJD;
    float* Wcat  = ws + off; off += (size_t)Cs * PROJD;
    float* qpts  = ws + off; off += (size_t)Nres * NH * NPQ * 3;
    float* sqq   = ws + off; off += (size_t)Nres * NH;
    float* kT    = ws + off; off += (size_t)NH * HC * Nres;
    float* kptsT = ws + off; off += (size_t)NH * NPQ * 3 * Nres;
    float* sqkT  = ws + off; off += (size_t)NH * Nres;
    float* vh    = ws + off; off += (size_t)Nres * VHD;
    float* catb  = ws + off; off += (size_t)Nres * CATD;
    float* Rbuf  = ws + off; off += (size_t)Nres * 9;
    float* tbuf  = ws + off; off += (size_t)Nres * 3;
    float* h1    = ws + off; off += (size_t)Nres * Cs;
    float* h2    = ws + off; off += (size_t)Nres * Cs;
    float* Pslab = ws + off; off += (size_t)11 * Nres * Cs;

    const int MNp = Nres * PROJD;
    const int MNs = Nres * Cs;

    k_init<<<gdiv(Nres*Cs, 256), 256, 0, stream>>>(s_in, s_cur, Rbuf, tbuf);
    k_concatW<<<gdiv(Cs*PROJD, 256), 256, 0, stream>>>(w_q, w_kv, w_qpts, w_kvpts, Wcat);
    k_bproj<<<Nres*Nres/16, 256, 0, stream>>>(z, w_b, b_hij);

    for (int it = 0; it < NBLK; it++) {
        // fused projections: proj = s_cur @ Wcat (512 x 384 x 1152), split-K=2
        k_gemm_sk<<<dim3(PROJD/64, Nres/64, 2), 256, 0, stream>>>(s_cur, Wcat, Pslab, Nres, Cs, PROJD, 192);
        k_reduce<<<gdiv(MNp, 256), 256, 0, stream>>>(Pslab, nullptr, proj, MNp, PROJD, 2, 0);
        // point transforms + staging
        k_prep<<<gdiv(NH*Nres, 256), 256, 0, stream>>>(proj, Rbuf, tbuf, qpts, sqq, kT, kptsT, sqkT, vh);
        // fused attention -> cat (grid: 512 residues x 3 head-groups)
        k_attn<<<dim3(Nres, 3), 256, 0, stream>>>(proj, qpts, sqq, kT, kptsT, sqkT, b_hij, hw, z, vh, Rbuf, tbuf, catb);
        // s += cat @ w_out + b_out (512 x 2112 x 384), split-K=11
        k_gemm_sk<<<dim3(Cs/64, Nres/64, 11), 256, 0, stream>>>(catb, w_out, Pslab, Nres, CATD, Cs, 192);
        k_reduce<<<gdiv(MNs, 256), 256, 0, stream>>>(Pslab, b_out, s_cur, MNs, Cs, 11, 2);
        k_ln<<<Nres, Cs, 0, stream>>>(s_cur, ln1_g, ln1_b);
        // transition (512 x 384 x 384), split-K=6
        k_gemm_sk<<<dim3(Cs/64, Nres/64, 6), 256, 0, stream>>>(s_cur, w_t1, Pslab, Nres, Cs, Cs, 64);
        k_reduce<<<gdiv(MNs, 256), 256, 0, stream>>>(Pslab, nullptr, h1, MNs, Cs, 6, 1);
        k_gemm_sk<<<dim3(Cs/64, Nres/64, 6), 256, 0, stream>>>(h1, w_t2, Pslab, Nres, Cs, Cs, 64);
        k_reduce<<<gdiv(MNs, 256), 256, 0, stream>>>(Pslab, nullptr, h2, MNs, Cs, 6, 1);
        k_gemm_sk<<<dim3(Cs/64, Nres/64, 6), 256, 0, stream>>>(h2, w_t3, Pslab, Nres, Cs, Cs, 64);
        k_reduce<<<gdiv(MNs, 256), 256, 0, stream>>>(Pslab, nullptr, s_cur, MNs, Cs, 6, 2);
        k_ln<<<Nres, Cs, 0, stream>>>(s_cur, ln2_g, ln2_b);
        // backbone update
        k_bb<<<Nres/4, 256, 0, stream>>>(s_cur, w_bb, b_bb, Rbuf, tbuf);
    }

    k_final<<<gdiv(Nres*(Cs+3), 256), 256, 0, stream>>>(s_cur, tbuf, out);
}

// Round 7
// 1790.374 us; speedup vs baseline: 1.4327x; 1.2353x over previous
//
#include <hip/hip_runtime.h>

// ---------------- problem constants ----------------
constexpr int Nres = 512;
constexpr int Cs   = 384;
constexpr int Cz   = 128;
constexpr int NH   = 12;
constexpr int HC   = 16;
constexpr int NPQ  = 4;
constexpr int NPV  = 8;
constexpr int NBLK = 8;
constexpr int PROJD = NH*HC + NH*2*HC + NH*NPQ*3 + NH*(NPQ+NPV)*3; // 1152
constexpr int CATD = NH*HC + NH*NPV*3 + NH*NPV + NH*Cz;            // 2112
constexpr int VHD  = NH * (HC + NPV*3);                             // 480
constexpr float W_L  = 0.57735026918962576f;  // sqrt(1/3)
constexpr float W_C2 = 0.11785113019775793f;  // sqrt(2/(9*PQ)) / 2

static inline int gdiv(int n, int b) { return (n + b - 1) / b; }

// ---------------- init ----------------
__global__ void k_init(const float* __restrict__ s_in, float* __restrict__ s_cur,
                       float* __restrict__ R, float* __restrict__ t) {
    int idx = blockIdx.x * blockDim.x + threadIdx.x;
    if (idx < Nres * Cs) s_cur[idx] = s_in[idx];
    if (idx < Nres * 9) {
        int e = idx % 9;
        R[idx] = (e == 0 || e == 4 || e == 8) ? 1.f : 0.f;
    }
    if (idx < Nres * 3) t[idx] = 0.f;
}

// concat projection weights into Wcat[384][1152]
__global__ void k_concatW(const float* __restrict__ w_q, const float* __restrict__ w_kv,
                          const float* __restrict__ w_qpts, const float* __restrict__ w_kvpts,
                          float* __restrict__ Wcat) {
    int idx = blockIdx.x * blockDim.x + threadIdx.x;
    if (idx >= Cs * PROJD) return;
    int k = idx / PROJD, n = idx - k * PROJD;
    float v;
    if      (n < 192) v = w_q[k * 192 + n];
    else if (n < 576) v = w_kv[k * 384 + (n - 192)];
    else if (n < 720) v = w_qpts[k * 144 + (n - 576)];
    else              v = w_kvpts[k * 432 + (n - 720)];
    Wcat[idx] = v;
}

// ---------------- split-K tiled GEMM ----------------
__global__ void __launch_bounds__(256)
k_gemm_sk(const float* __restrict__ A, const float* __restrict__ B,
          float* __restrict__ P, int M, int K, int N, int Kc) {
    __shared__ float As[32][66];
    __shared__ float Bs[32][64];
    const int tid = threadIdx.x;
    const int tx = tid & 15;
    const int ty = tid >> 4;
    const int m0 = blockIdx.y * 64;
    const int n0 = blockIdx.x * 64;
    const int kbeg = blockIdx.z * Kc;

    float acc[4][4] = {};

    for (int k0 = kbeg; k0 < kbeg + Kc; k0 += 32) {
#pragma unroll
        for (int l = 0; l < 8; l++) {
            int idx = tid + l * 256;
            int ak = idx & 31, am = idx >> 5;
            As[ak][am] = A[(size_t)(m0 + am) * K + k0 + ak];
        }
#pragma unroll
        for (int l = 0; l < 8; l++) {
            int idx = tid + l * 256;
            int bk = idx >> 6, bn = idx & 63;
            Bs[bk][bn] = B[(size_t)(k0 + bk) * N + n0 + bn];
        }
        __syncthreads();
#pragma unroll
        for (int kk = 0; kk < 32; kk++) {
            float2 a01 = *(const float2*)&As[kk][ty * 4];
            float2 a23 = *(const float2*)&As[kk][ty * 4 + 2];
            float4 b4  = *(const float4*)&Bs[kk][tx * 4];
            acc[0][0] += a01.x * b4.x; acc[0][1] += a01.x * b4.y;
            acc[0][2] += a01.x * b4.z; acc[0][3] += a01.x * b4.w;
            acc[1][0] += a01.y * b4.x; acc[1][1] += a01.y * b4.y;
            acc[1][2] += a01.y * b4.z; acc[1][3] += a01.y * b4.w;
            acc[2][0] += a23.x * b4.x; acc[2][1] += a23.x * b4.y;
            acc[2][2] += a23.x * b4.z; acc[2][3] += a23.x * b4.w;
            acc[3][0] += a23.y * b4.x; acc[3][1] += a23.y * b4.y;
            acc[3][2] += a23.y * b4.z; acc[3][3] += a23.y * b4.w;
        }
        __syncthreads();
    }
    float* Pp = P + (size_t)blockIdx.z * M * N;
#pragma unroll
    for (int r = 0; r < 4; r++) {
        float4 v = make_float4(acc[r][0], acc[r][1], acc[r][2], acc[r][3]);
        *(float4*)&Pp[(size_t)(m0 + ty * 4 + r) * N + n0 + tx * 4] = v;
    }
}

// reduce partials: mode 0 store, 1 relu-store, 2 accumulate into out
__global__ void k_reduce(const float* __restrict__ P, const float* __restrict__ bias,
                         float* __restrict__ out, int MN, int N, int nsplit, int mode) {
    int idx = blockIdx.x * blockDim.x + threadIdx.x;
    if (idx >= MN) return;
    float v = 0.f;
    for (int s = 0; s < nsplit; s++) v += P[(size_t)s * MN + idx];
    if (bias) v += bias[idx % N];
    if (mode == 1) v = fmaxf(v, 0.f);
    if (mode == 2) out[idx] += v;
    else           out[idx] = v;
}

// ---------------- b_hij (once) ----------------
__global__ void k_bproj(const float* __restrict__ z, const float* __restrict__ w_b,
                        float* __restrict__ b_hij) {
    __shared__ float zs[16][129];
    __shared__ float wbs[Cz * NH];
    const int tid = threadIdx.x;
    const int base = blockIdx.x * 16;
#pragma unroll
    for (int l = 0; l < 6; l++) {
        int idx = tid + l * 256;
        if (idx < Cz * NH) wbs[idx] = w_b[idx];
    }
#pragma unroll
    for (int l = 0; l < 8; l++) {
        int idx = tid + l * 256;
        int r = idx >> 7, c = idx & 127;
        zs[r][c] = z[(size_t)(base + r) * Cz + c];
    }
    __syncthreads();
    if (tid < 192) {
        int h = tid >> 4, r = tid & 15;
        float acc = 0.f;
        for (int c = 0; c < Cz; c++) acc += zs[r][c] * wbs[c * NH + h];
        int row = base + r;
        int i = row >> 9, j = row & 511;
        b_hij[((size_t)h * Nres + i) * Nres + j] = acc;
    }
}

// ---------------- prep: transform points, build staging (kT, kptsT, sqkT, vh) ----------------
__global__ void k_prep(const float* __restrict__ proj, const float* __restrict__ R,
                       const float* __restrict__ t,
                       float* __restrict__ qpts, float* __restrict__ sqq,
                       float* __restrict__ kT, float* __restrict__ kptsT,
                       float* __restrict__ sqkT, float* __restrict__ vh) {
    int idx = blockIdx.x * blockDim.x + threadIdx.x;
    if (idx >= NH * Nres) return;
    int h = idx / Nres, i = idx % Nres;
    float R_[9], t_[3];
#pragma unroll
    for (int e = 0; e < 9; e++) R_[e] = R[i * 9 + e];
#pragma unroll
    for (int e = 0; e < 3; e++) t_[e] = t[i * 3 + e];
    const float* prow = proj + (size_t)i * PROJD;
    float* vrow = vh + (size_t)i * VHD + h * 40;

    float sq = 0.f;
#pragma unroll
    for (int p = 0; p < NPQ; p++) {
        const float* src = prow + 576 + (h * NPQ + p) * 3;
        float y0 = src[0], y1 = src[1], y2 = src[2];
        float v0 = R_[0]*y0 + R_[1]*y1 + R_[2]*y2 + t_[0];
        float v1 = R_[3]*y0 + R_[4]*y1 + R_[5]*y2 + t_[1];
        float v2 = R_[6]*y0 + R_[7]*y1 + R_[8]*y2 + t_[2];
        float* dst = qpts + (size_t)i * (NH*NPQ*3) + h * NPQ*3 + p * 3;
        dst[0] = v0; dst[1] = v1; dst[2] = v2;
        sq += v0*v0 + v1*v1 + v2*v2;
    }
    sqq[i * NH + h] = sq;

    float sk = 0.f;
#pragma unroll
    for (int p = 0; p < NPQ + NPV; p++) {
        const float* src = prow + 720 + (h * (NPQ+NPV) + p) * 3;
        float y0 = src[0], y1 = src[1], y2 = src[2];
        float v0 = R_[0]*y0 + R_[1]*y1 + R_[2]*y2 + t_[0];
        float v1 = R_[3]*y0 + R_[4]*y1 + R_[5]*y2 + t_[1];
        float v2 = R_[6]*y0 + R_[7]*y1 + R_[8]*y2 + t_[2];
        if (p < NPQ) {
            kptsT[((size_t)h * (NPQ*3) + p*3 + 0) * Nres + i] = v0;
            kptsT[((size_t)h * (NPQ*3) + p*3 + 1) * Nres + i] = v1;
            kptsT[((size_t)h * (NPQ*3) + p*3 + 2) * Nres + i] = v2;
            sk += v0*v0 + v1*v1 + v2*v2;
        } else {
            int c0 = 16 + (p - NPQ) * 3;
            vrow[c0 + 0] = v0; vrow[c0 + 1] = v1; vrow[c0 + 2] = v2;
        }
    }
    sqkT[h * Nres + i] = sk;

#pragma unroll
    for (int c = 0; c < HC; c++) {
        kT[((size_t)h * HC + c) * Nres + i] = prow[192 + h * 2 * HC + c];
        vrow[c] = prow[192 + h * 2 * HC + HC + c];
    }
}

// ---------------- attention part 1: logits + softmax + o + o_pt ----------------
// grid (Nres, 3): block (i, hg) handles heads hg*4 .. hg*4+3; probs -> attnP[i][h][j]
__global__ void __launch_bounds__(256)
k_attn_sm(const float* __restrict__ proj, const float* __restrict__ qpts,
          const float* __restrict__ sqq, const float* __restrict__ kT,
          const float* __restrict__ kptsT, const float* __restrict__ sqkT,
          const float* __restrict__ b_hij, const float* __restrict__ hw,
          const float* __restrict__ vh,
          const float* __restrict__ R, const float* __restrict__ t,
          float* __restrict__ attnP, float* __restrict__ cat) {
    __shared__ float a_sT[512 * 5];      // probs [j][h], stride 5 (coprime 32)
    __shared__ float qs[4 * HC];
    __shared__ float qp[4 * 12];
    __shared__ float sqq_s[4];
    __shared__ float gam[4];
    __shared__ float optg_s[4 * NPV * 3];  // 96

    const int i  = blockIdx.x;
    const int hg = blockIdx.y;
    const int tid = threadIdx.x;

    if (tid < 64) qs[tid] = proj[(size_t)i * PROJD + hg * 64 + tid];
    if (tid < 48) qp[tid] = qpts[(size_t)i * 144 + hg * 48 + tid];
    if (tid < 4) {
        sqq_s[tid] = sqq[i * NH + hg * 4 + tid];
        gam[tid] = log1pf(__expf(hw[hg * 4 + tid]));
    }
    __syncthreads();

    // ---- logits: 4 heads x 512 j ----
#pragma unroll
    for (int l = 0; l < 8; l++) {
        int idx = tid + l * 256;
        int h = idx >> 9, j = idx & 511;
        int hglob = hg * 4 + h;
        float sc = 0.f;
#pragma unroll
        for (int c = 0; c < HC; c++) sc += qs[h * 16 + c] * kT[((size_t)hglob * HC + c) * Nres + j];
        sc *= 0.25f;
        float cr = 0.f;
#pragma unroll
        for (int e = 0; e < 12; e++) cr += qp[h * 12 + e] * kptsT[((size_t)hglob * 12 + e) * Nres + j];
        float d2 = sqq_s[h] + sqkT[hglob * Nres + j] - 2.f * cr;
        a_sT[j * 5 + h] = W_L * (sc + b_hij[((size_t)hglob * Nres + i) * Nres + j] - gam[h] * W_C2 * d2);
    }
    __syncthreads();

    // ---- softmax: wave wv handles local head wv; write probs to LDS + global ----
    {
        int wv = tid >> 6, ln = tid & 63;
        int hglob = hg * 4 + wv;
        float vals[8];
        float m = -1e30f;
#pragma unroll
        for (int jj = 0; jj < 8; jj++) { vals[jj] = a_sT[(ln + jj * 64) * 5 + wv]; m = fmaxf(m, vals[jj]); }
#pragma unroll
        for (int off = 32; off > 0; off >>= 1) m = fmaxf(m, __shfl_xor(m, off));
        float sm = 0.f;
#pragma unroll
        for (int jj = 0; jj < 8; jj++) { vals[jj] = __expf(vals[jj] - m); sm += vals[jj]; }
#pragma unroll
        for (int off = 32; off > 0; off >>= 1) sm += __shfl_xor(sm, off);
        float inv = 1.f / sm;
        float* aP = attnP + ((size_t)i * NH + hglob) * Nres;
#pragma unroll
        for (int jj = 0; jj < 8; jj++) {
            float p = vals[jj] * inv;
            a_sT[(ln + jj * 64) * 5 + wv] = p;
            aP[ln + jj * 64] = p;
        }
    }
    __syncthreads();

    float* crow = cat + (size_t)i * CATD;

    // ---- o + o_pt(global): 160 outputs (4 heads x 40) ----
    if (tid < 160) {
        int h = tid / 40;
        int c = tid - h * 40;
        int hglob = hg * 4 + h;
        float acc = 0.f;
        const float* vcol = vh + hglob * 40 + c;
#pragma unroll 8
        for (int j = 0; j < Nres; j++)
            acc += a_sT[j * 5 + h] * vcol[(size_t)j * VHD];
        if (c < 16) crow[hglob * 16 + c] = acc;
        else        optg_s[h * 24 + (c - 16)] = acc;
    }
    __syncthreads();

    // ---- o_pt local transform + norms ----
    if (tid < 32) {
        int h = tid >> 3, p = tid & 7;
        int hglob = hg * 4 + h;
        float g0 = optg_s[h * 24 + p * 3 + 0];
        float g1 = optg_s[h * 24 + p * 3 + 1];
        float g2 = optg_s[h * 24 + p * 3 + 2];
        float d0 = g0 - t[i * 3 + 0], d1 = g1 - t[i * 3 + 1], d2v = g2 - t[i * 3 + 2];
        const float* Rn = R + i * 9;
        float l0 = Rn[0] * d0 + Rn[3] * d1 + Rn[6] * d2v;
        float l1 = Rn[1] * d0 + Rn[4] * d1 + Rn[7] * d2v;
        float l2 = Rn[2] * d0 + Rn[5] * d1 + Rn[8] * d2v;
        int hp = hglob * NPV + p;
        crow[192 + hp * 3 + 0] = l0;
        crow[192 + hp * 3 + 1] = l1;
        crow[192 + hp * 3 + 2] = l2;
        crow[480 + hp] = sqrtf(l0 * l0 + l1 * l1 + l2 * l2 + 1e-8f);
    }
}

// ---------------- attention part 2: o_pair, one z pass ----------------
// grid (Nres, 2): block (i, half) handles j in [half*256, half*256+256)
// 256 threads = 8 j-groups x 32 float4 lanes; partials -> P2[half][i][1536]
__global__ void __launch_bounds__(256)
k_opair(const float* __restrict__ attnP, const float* __restrict__ z,
        float* __restrict__ P2) {
    __shared__ float lds[4608];   // probs [12][256] (3072) then red buffer (4608)
    const int i = blockIdx.x, half = blockIdx.y;
    const int tid = threadIdx.x;

    // stage probs
#pragma unroll
    for (int l = 0; l < 12; l++) {
        int idx = tid + l * 256;
        int h = idx >> 8, j = idx & 255;
        lds[h * 256 + j] = attnP[((size_t)i * NH + h) * Nres + half * 256 + j];
    }
    __syncthreads();

    const int grp = tid >> 5, zc4 = tid & 31;
    const float4* z4 = (const float4*)(z + ((size_t)i * Nres + half * 256) * Cz);
    float4 accp[NH];
#pragma unroll
    for (int h = 0; h < NH; h++) accp[h] = make_float4(0.f, 0.f, 0.f, 0.f);

#pragma unroll 8
    for (int jj = 0; jj < 32; jj++) {
        int j = grp * 32 + jj;
        float4 zv = z4[j * 32 + zc4];
#pragma unroll
        for (int h = 0; h < NH; h++) {
            float a = lds[h * 256 + j];
            accp[h].x += a * zv.x; accp[h].y += a * zv.y;
            accp[h].z += a * zv.z; accp[h].w += a * zv.w;
        }
    }
    __syncthreads();   // probs dead

    // combine group pairs within wave
#pragma unroll
    for (int h = 0; h < NH; h++) {
        accp[h].x += __shfl_xor(accp[h].x, 32);
        accp[h].y += __shfl_xor(accp[h].y, 32);
        accp[h].z += __shfl_xor(accp[h].z, 32);
        accp[h].w += __shfl_xor(accp[h].w, 32);
    }
    const int wv = tid >> 6, ln = tid & 63;
    float4* red4 = (float4*)lds;
    if (wv >= 1 && ln < 32) {
#pragma unroll
        for (int h = 0; h < NH; h++) red4[(wv - 1) * 384 + h * 32 + ln] = accp[h];
    }
    __syncthreads();
    if (wv == 0 && ln < 32) {
        float4* out4 = (float4*)(P2 + ((size_t)half * Nres + i) * (NH * Cz));
#pragma unroll
        for (int h = 0; h < NH; h++) {
            float4 v = accp[h];
#pragma unroll
            for (int w = 0; w < 3; w++) {
                float4 r = red4[w * 384 + h * 32 + ln];
                v.x += r.x; v.y += r.y; v.z += r.z; v.w += r.w;
            }
            out4[h * 32 + ln] = v;
        }
    }
}

// add the two j-half partials into cat[:, 576:]
__global__ void k_opair_red(const float* __restrict__ P2, float* __restrict__ cat) {
    int idx = blockIdx.x * blockDim.x + threadIdx.x;
    if (idx >= Nres * NH * Cz) return;
    int i = idx / (NH * Cz), c = idx - i * (NH * Cz);
    cat[(size_t)i * CATD + 576 + c] =
        P2[(size_t)i * (NH * Cz) + c] + P2[(size_t)(Nres + i) * (NH * Cz) + c];
}

// ---------------- LayerNorm ----------------
__global__ void k_ln(float* __restrict__ s, const float* __restrict__ g,
                     const float* __restrict__ b) {
    __shared__ float red[512];
    int i = blockIdx.x, tid = threadIdx.x;
    float v = s[(size_t)i * Cs + tid];
    red[tid] = v;
    if (tid < 128) red[384 + tid] = 0.f;
    __syncthreads();
    for (int st = 256; st > 0; st >>= 1) { if (tid < st) red[tid] += red[tid + st]; __syncthreads(); }
    float mean = red[0] / Cs;
    __syncthreads();
    float d = v - mean;
    red[tid] = d * d;
    if (tid < 128) red[384 + tid] = 0.f;
    __syncthreads();
    for (int st = 256; st > 0; st >>= 1) { if (tid < st) red[tid] += red[tid + st]; __syncthreads(); }
    float var = red[0] / Cs;
    s[(size_t)i * Cs + tid] = d * rsqrtf(var + 1e-5f) * g[tid] + b[tid];
}

// ---------------- backbone update: one wave per residue ----------------
__global__ void k_bb(const float* __restrict__ s, const float* __restrict__ w_bb,
                     const float* __restrict__ b_bb, float* __restrict__ R, float* __restrict__ t) {
    int wv = threadIdx.x >> 6, lane = threadIdx.x & 63;
    int i = blockIdx.x * 4 + wv;
    const float* sr = s + (size_t)i * Cs;
    float u[6] = {};
#pragma unroll
    for (int k6 = 0; k6 < 6; k6++) {
        int k = lane + k6 * 64;
        float sv = sr[k];
#pragma unroll
        for (int d = 0; d < 6; d++) u[d] += sv * w_bb[k * 6 + d];
    }
#pragma unroll
    for (int off = 32; off > 0; off >>= 1)
#pragma unroll
        for (int d = 0; d < 6; d++) u[d] += __shfl_down(u[d], off);
    if (lane == 0) {
#pragma unroll
        for (int d = 0; d < 6; d++) u[d] += b_bb[d];
        float qb = u[0], qc = u[1], qd = u[2];
        float inv = rsqrtf(1.f + qb*qb + qc*qc + qd*qd);
        float w = inv, x = qb * inv, y = qc * inv, zq = qd * inv;
        float Ru[9] = {
            1.f - 2.f*(y*y + zq*zq), 2.f*(x*y - w*zq),       2.f*(x*zq + w*y),
            2.f*(x*y + w*zq),        1.f - 2.f*(x*x + zq*zq), 2.f*(y*zq - w*x),
            2.f*(x*zq - w*y),        2.f*(y*zq + w*x),        1.f - 2.f*(x*x + y*y)
        };
        float Ro[9];
#pragma unroll
        for (int e = 0; e < 9; e++) Ro[e] = R[i * 9 + e];
        float tu0 = u[3], tu1 = u[4], tu2 = u[5];
        t[i*3+0] += Ro[0]*tu0 + Ro[1]*tu1 + Ro[2]*tu2;
        t[i*3+1] += Ro[3]*tu0 + Ro[4]*tu1 + Ro[5]*tu2;
        t[i*3+2] += Ro[6]*tu0 + Ro[7]*tu1 + Ro[8]*tu2;
#pragma unroll
        for (int r = 0; r < 3; r++)
#pragma unroll
            for (int c = 0; c < 3; c++)
                R[i*9 + r*3 + c] = Ro[r*3+0]*Ru[0*3+c] + Ro[r*3+1]*Ru[1*3+c] + Ro[r*3+2]*Ru[2*3+c];
    }
}

// ---------------- final pack ----------------
__global__ void k_final(const float* __restrict__ s, const float* __restrict__ t,
                        float* __restrict__ out) {
    int idx = blockIdx.x * blockDim.x + threadIdx.x;
    if (idx >= Nres * (Cs + 3)) return;
    int i = idx / (Cs + 3), c = idx - i * (Cs + 3);
    out[idx] = (c < Cs) ? s[(size_t)i * Cs + c] : t[i * 3 + (c - Cs)];
}

// ---------------- launch ----------------
extern "C" void kernel_launch(void* const* d_in, const int* in_sizes, int n_in,
                              void* d_out, int out_size, void* d_ws, size_t ws_size,
                              hipStream_t stream) {
    const float* s_in    = (const float*)d_in[0];
    const float* z       = (const float*)d_in[1];
    const float* w_q     = (const float*)d_in[2];
    const float* w_kv    = (const float*)d_in[3];
    const float* w_qpts  = (const float*)d_in[4];
    const float* w_kvpts = (const float*)d_in[5];
    const float* w_b     = (const float*)d_in[6];
    const float* hw      = (const float*)d_in[7];
    const float* w_out   = (const float*)d_in[8];
    const float* b_out   = (const float*)d_in[9];
    const float* ln1_g   = (const float*)d_in[10];
    const float* ln1_b   = (const float*)d_in[11];
    const float* w_t1    = (const float*)d_in[12];
    const float* w_t2    = (const float*)d_in[13];
    const float* w_t3    = (const float*)d_in[14];
    const float* ln2_g   = (const float*)d_in[15];
    const float* ln2_b   = (const float*)d_in[16];
    const float* w_bb    = (const float*)d_in[17];
    const float* b_bb    = (const float*)d_in[18];
    float* out = (float*)d_out;

    float* ws = (float*)d_ws;
    size_t off = 0;
    float* s_cur = ws + off; off += (size_t)Nres * Cs;
    float* b_hij = ws + off; off += (size_t)NH * Nres * Nres;
    float* proj  = ws + off; off += (size_t)Nres * PROJD;
    float* Wcat  = ws + off; off += (size_t)Cs * PROJD;
    float* qpts  = ws + off; off += (size_t)Nres * NH * NPQ * 3;
    float* sqq   = ws + off; off += (size_t)Nres * NH;
    float* kT    = ws + off; off += (size_t)NH * HC * Nres;
    float* kptsT = ws + off; off += (size_t)NH * NPQ * 3 * Nres;
    float* sqkT  = ws + off; off += (size_t)NH * Nres;
    float* vh    = ws + off; off += (size_t)Nres * VHD;
    float* catb  = ws + off; off += (size_t)Nres * CATD;
    float* Rbuf  = ws + off; off += (size_t)Nres * 9;
    float* tbuf  = ws + off; off += (size_t)Nres * 3;
    float* h1    = ws + off; off += (size_t)Nres * Cs;
    float* h2    = ws + off; off += (size_t)Nres * Cs;
    float* Pslab = ws + off; off += (size_t)11 * Nres * Cs;
    float* attnP = ws + off; off += (size_t)Nres * NH * Nres;      // 3.1M floats
    float* P2    = ws + off; off += (size_t)2 * Nres * NH * Cz;    // 1.6M floats

    const int MNp = Nres * PROJD;
    const int MNs = Nres * Cs;

    k_init<<<gdiv(Nres*Cs, 256), 256, 0, stream>>>(s_in, s_cur, Rbuf, tbuf);
    k_concatW<<<gdiv(Cs*PROJD, 256), 256, 0, stream>>>(w_q, w_kv, w_qpts, w_kvpts, Wcat);
    k_bproj<<<Nres*Nres/16, 256, 0, stream>>>(z, w_b, b_hij);

    for (int it = 0; it < NBLK; it++) {
        // fused projections: proj = s_cur @ Wcat (512 x 384 x 1152), split-K=2
        k_gemm_sk<<<dim3(PROJD/64, Nres/64, 2), 256, 0, stream>>>(s_cur, Wcat, Pslab, Nres, Cs, PROJD, 192);
        k_reduce<<<gdiv(MNp, 256), 256, 0, stream>>>(Pslab, nullptr, proj, MNp, PROJD, 2, 0);
        // point transforms + staging
        k_prep<<<gdiv(NH*Nres, 256), 256, 0, stream>>>(proj, Rbuf, tbuf, qpts, sqq, kT, kptsT, sqkT, vh);
        // attention: logits/softmax/o/o_pt  +  o_pair (single z pass)
        k_attn_sm<<<dim3(Nres, 3), 256, 0, stream>>>(proj, qpts, sqq, kT, kptsT, sqkT, b_hij, hw, vh, Rbuf, tbuf, attnP, catb);
        k_opair<<<dim3(Nres, 2), 256, 0, stream>>>(attnP, z, P2);
        k_opair_red<<<gdiv(Nres*NH*Cz, 256), 256, 0, stream>>>(P2, catb);
        // s += cat @ w_out + b_out (512 x 2112 x 384), split-K=11
        k_gemm_sk<<<dim3(Cs/64, Nres/64, 11), 256, 0, stream>>>(catb, w_out, Pslab, Nres, CATD, Cs, 192);
        k_reduce<<<gdiv(MNs, 256), 256, 0, stream>>>(Pslab, b_out, s_cur, MNs, Cs, 11, 2);
        k_ln<<<Nres, Cs, 0, stream>>>(s_cur, ln1_g, ln1_b);
        // transition (512 x 384 x 384), split-K=6
        k_gemm_sk<<<dim3(Cs/64, Nres/64, 6), 256, 0, stream>>>(s_cur, w_t1, Pslab, Nres, Cs, Cs, 64);
        k_reduce<<<gdiv(MNs, 256), 256, 0, stream>>>(Pslab, nullptr, h1, MNs, Cs, 6, 1);
        k_gemm_sk<<<dim3(Cs/64, Nres/64, 6), 256, 0, stream>>>(h1, w_t2, Pslab, Nres, Cs, Cs, 64);
        k_reduce<<<gdiv(MNs, 256), 256, 0, stream>>>(Pslab, nullptr, h2, MNs, Cs, 6, 1);
        k_gemm_sk<<<dim3(Cs/64, Nres/64, 6), 256, 0, stream>>>(h2, w_t3, Pslab, Nres, Cs, Cs, 64);
        k_reduce<<<gdiv(MNs, 256), 256, 0, stream>>>(Pslab, nullptr, s_cur, MNs, Cs, 6, 2);
        k_ln<<<Nres, Cs, 0, stream>>>(s_cur, ln2_g, ln2_b);
        // backbone update
        k_bb<<<Nres/4, 256, 0, stream>>>(s_cur, w_bb, b_bb, Rbuf, tbuf);
    }

    k_final<<<gdiv(Nres*(Cs+3), 256), 256, 0, stream>>>(s_cur, tbuf, out);
}

// Round 8
// 1524.745 us; speedup vs baseline: 1.6823x; 1.1742x over previous
//
#include <hip/hip_runtime.h>
#include <hip/hip_bf16.h>

// ---------------- problem constants ----------------
constexpr int Nres = 512;
constexpr int Cs   = 384;
constexpr int Cz   = 128;
constexpr int NH   = 12;
constexpr int HC   = 16;
constexpr int NPQ  = 4;
constexpr int NPV  = 8;
constexpr int NBLK = 8;
constexpr int PROJD = NH*HC + NH*2*HC + NH*NPQ*3 + NH*(NPQ+NPV)*3; // 1152
constexpr int CATD = NH*HC + NH*NPV*3 + NH*NPV + NH*Cz;            // 2112
constexpr int VHD  = NH * (HC + NPV*3);                             // 480
constexpr float W_L  = 0.57735026918962576f;  // sqrt(1/3)
constexpr float W_C2 = 0.11785113019775793f;  // sqrt(2/(9*PQ)) / 2

using u16 = unsigned short;
typedef __bf16 bf16x8 __attribute__((ext_vector_type(8)));
typedef float  f32x4  __attribute__((ext_vector_type(4)));

static inline int gdiv(int n, int b) { return (n + b - 1) / b; }

static __device__ __forceinline__ u16 f2bf(float x) {
    __hip_bfloat16 h = __float2bfloat16(x);
    return *reinterpret_cast<u16*>(&h);
}

// ---------------- init ----------------
__global__ void k_init(const float* __restrict__ s_in, float* __restrict__ s_cur,
                       u16* __restrict__ s_bf,
                       float* __restrict__ R, float* __restrict__ t) {
    int idx = blockIdx.x * blockDim.x + threadIdx.x;
    if (idx < Nres * Cs) { float v = s_in[idx]; s_cur[idx] = v; s_bf[idx] = f2bf(v); }
    if (idx < Nres * 9) {
        int e = idx % 9;
        R[idx] = (e == 0 || e == 4 || e == 8) ? 1.f : 0.f;
    }
    if (idx < Nres * 3) t[idx] = 0.f;
}

// concat projection weights into Wcat[384][1152] (fp32 staging for transpose)
__global__ void k_concatW(const float* __restrict__ w_q, const float* __restrict__ w_kv,
                          const float* __restrict__ w_qpts, const float* __restrict__ w_kvpts,
                          float* __restrict__ Wcat) {
    int idx = blockIdx.x * blockDim.x + threadIdx.x;
    if (idx >= Cs * PROJD) return;
    int k = idx / PROJD, n = idx - k * PROJD;
    float v;
    if      (n < 192) v = w_q[k * 192 + n];
    else if (n < 576) v = w_kv[k * 384 + (n - 192)];
    else if (n < 720) v = w_qpts[k * 144 + (n - 576)];
    else              v = w_kvpts[k * 432 + (n - 720)];
    Wcat[idx] = v;
}

// transpose + bf16 convert: out[n][k] = in[k][n]; K,N multiples of 32
__global__ void k_transposeW(const float* __restrict__ in, u16* __restrict__ out,
                             int K, int N) {
    __shared__ float tile[32][33];
    int n0 = blockIdx.x * 32, k0 = blockIdx.y * 32;
    int tx = threadIdx.x & 31, ty = threadIdx.x >> 5;   // ty 0..7
#pragma unroll
    for (int j = 0; j < 4; j++)
        tile[ty + j * 8][tx] = in[(size_t)(k0 + ty + j * 8) * N + n0 + tx];
    __syncthreads();
#pragma unroll
    for (int j = 0; j < 4; j++)
        out[(size_t)(n0 + ty + j * 8) * K + k0 + tx] = f2bf(tile[tx][ty + j * 8]);
}

// ---------------- split-K MFMA GEMM (bf16 inputs, fp32 partials) ----------------
// A[M][K] bf16, Bt[N][K] bf16 (pre-transposed). grid (N/64, M/64, nsplit).
// tile 64x64, BK=32; 4 waves in 2x2, each wave 32x32 via 2x2 mfma_16x16x32.
__global__ void __launch_bounds__(256)
k_gemm_mfma(const u16* __restrict__ A, const u16* __restrict__ Bt,
            float* __restrict__ P, int M, int K, int N, int Kc) {
    __shared__ u16 As[64 * 40];   // row pad 40 bf16 (80 B): 2-way bank alias only
    __shared__ u16 Bs[64 * 40];
    const int tid = threadIdx.x;
    const int m0 = blockIdx.y * 64;
    const int n0 = blockIdx.x * 64;
    const int kbeg = blockIdx.z * Kc;
    const int wv = tid >> 6, lane = tid & 63;
    const int wm = (wv >> 1) * 32, wn = (wv & 1) * 32;
    const int lrow = lane & 15, lq = lane >> 4;

    f32x4 zero = {0.f, 0.f, 0.f, 0.f};
    f32x4 acc00 = zero, acc01 = zero, acc10 = zero, acc11 = zero;

    const int srow = tid >> 2;          // 0..63
    const int sko  = (tid & 3) * 8;     // 0,8,16,24

    for (int k0 = kbeg; k0 < kbeg + Kc; k0 += 32) {
        *(uint4*)&As[srow * 40 + sko] = *(const uint4*)&A[(size_t)(m0 + srow) * K + k0 + sko];
        *(uint4*)&Bs[srow * 40 + sko] = *(const uint4*)&Bt[(size_t)(n0 + srow) * K + k0 + sko];
        __syncthreads();
        bf16x8 a0 = *reinterpret_cast<const bf16x8*>(&As[(wm + lrow) * 40 + lq * 8]);
        bf16x8 a1 = *reinterpret_cast<const bf16x8*>(&As[(wm + 16 + lrow) * 40 + lq * 8]);
        bf16x8 b0 = *reinterpret_cast<const bf16x8*>(&Bs[(wn + lrow) * 40 + lq * 8]);
        bf16x8 b1 = *reinterpret_cast<const bf16x8*>(&Bs[(wn + 16 + lrow) * 40 + lq * 8]);
        acc00 = __builtin_amdgcn_mfma_f32_16x16x32_bf16(a0, b0, acc00, 0, 0, 0);
        acc01 = __builtin_amdgcn_mfma_f32_16x16x32_bf16(a0, b1, acc01, 0, 0, 0);
        acc10 = __builtin_amdgcn_mfma_f32_16x16x32_bf16(a1, b0, acc10, 0, 0, 0);
        acc11 = __builtin_amdgcn_mfma_f32_16x16x32_bf16(a1, b1, acc11, 0, 0, 0);
        __syncthreads();
    }
    // C/D layout: col = lane&15, row = (lane>>4)*4 + reg   [m89/m91 verified]
    float* Pp = P + (size_t)blockIdx.z * M * N;
    const int rbase = m0 + wm + lq * 4;
    const int cbase = n0 + wn + lrow;
#pragma unroll
    for (int r = 0; r < 4; r++) {
        Pp[(size_t)(rbase + r) * N + cbase]           = acc00[r];
        Pp[(size_t)(rbase + r) * N + cbase + 16]      = acc01[r];
        Pp[(size_t)(rbase + 16 + r) * N + cbase]      = acc10[r];
        Pp[(size_t)(rbase + 16 + r) * N + cbase + 16] = acc11[r];
    }
}

// reduce partials (fp32 out): mode 0 store, 2 accumulate (+bias)
__global__ void k_reduce(const float* __restrict__ P, const float* __restrict__ bias,
                         float* __restrict__ out, int MN, int N, int nsplit, int mode) {
    int idx = blockIdx.x * blockDim.x + threadIdx.x;
    if (idx >= MN) return;
    float v = 0.f;
    for (int s = 0; s < nsplit; s++) v += P[(size_t)s * MN + idx];
    if (bias) v += bias[idx % N];
    if (mode == 2) out[idx] += v;
    else           out[idx] = v;
}

// reduce partials -> relu -> bf16 store
__global__ void k_reduce_relu_bf(const float* __restrict__ P, u16* __restrict__ out,
                                 int MN, int nsplit) {
    int idx = blockIdx.x * blockDim.x + threadIdx.x;
    if (idx >= MN) return;
    float v = 0.f;
    for (int s = 0; s < nsplit; s++) v += P[(size_t)s * MN + idx];
    out[idx] = f2bf(fmaxf(v, 0.f));
}

// ---------------- b_hij (once) ----------------
__global__ void k_bproj(const float* __restrict__ z, const float* __restrict__ w_b,
                        float* __restrict__ b_hij) {
    __shared__ float zs[16][129];
    __shared__ float wbs[Cz * NH];
    const int tid = threadIdx.x;
    const int base = blockIdx.x * 16;
#pragma unroll
    for (int l = 0; l < 6; l++) {
        int idx = tid + l * 256;
        if (idx < Cz * NH) wbs[idx] = w_b[idx];
    }
#pragma unroll
    for (int l = 0; l < 8; l++) {
        int idx = tid + l * 256;
        int r = idx >> 7, c = idx & 127;
        zs[r][c] = z[(size_t)(base + r) * Cz + c];
    }
    __syncthreads();
    if (tid < 192) {
        int h = tid >> 4, r = tid & 15;
        float acc = 0.f;
        for (int c = 0; c < Cz; c++) acc += zs[r][c] * wbs[c * NH + h];
        int row = base + r;
        int i = row >> 9, j = row & 511;
        b_hij[((size_t)h * Nres + i) * Nres + j] = acc;
    }
}

// ---------------- prep: transform points, build staging (kT, kptsT, sqkT, vh) ----------------
__global__ void k_prep(const float* __restrict__ proj, const float* __restrict__ R,
                       const float* __restrict__ t,
                       float* __restrict__ qpts, float* __restrict__ sqq,
                       float* __restrict__ kT, float* __restrict__ kptsT,
                       float* __restrict__ sqkT, float* __restrict__ vh) {
    int idx = blockIdx.x * blockDim.x + threadIdx.x;
    if (idx >= NH * Nres) return;
    int h = idx / Nres, i = idx % Nres;
    float R_[9], t_[3];
#pragma unroll
    for (int e = 0; e < 9; e++) R_[e] = R[i * 9 + e];
#pragma unroll
    for (int e = 0; e < 3; e++) t_[e] = t[i * 3 + e];
    const float* prow = proj + (size_t)i * PROJD;
    float* vrow = vh + (size_t)i * VHD + h * 40;

    float sq = 0.f;
#pragma unroll
    for (int p = 0; p < NPQ; p++) {
        const float* src = prow + 576 + (h * NPQ + p) * 3;
        float y0 = src[0], y1 = src[1], y2 = src[2];
        float v0 = R_[0]*y0 + R_[1]*y1 + R_[2]*y2 + t_[0];
        float v1 = R_[3]*y0 + R_[4]*y1 + R_[5]*y2 + t_[1];
        float v2 = R_[6]*y0 + R_[7]*y1 + R_[8]*y2 + t_[2];
        float* dst = qpts + (size_t)i * (NH*NPQ*3) + h * NPQ*3 + p * 3;
        dst[0] = v0; dst[1] = v1; dst[2] = v2;
        sq += v0*v0 + v1*v1 + v2*v2;
    }
    sqq[i * NH + h] = sq;

    float sk = 0.f;
#pragma unroll
    for (int p = 0; p < NPQ + NPV; p++) {
        const float* src = prow + 720 + (h * (NPQ+NPV) + p) * 3;
        float y0 = src[0], y1 = src[1], y2 = src[2];
        float v0 = R_[0]*y0 + R_[1]*y1 + R_[2]*y2 + t_[0];
        float v1 = R_[3]*y0 + R_[4]*y1 + R_[5]*y2 + t_[1];
        float v2 = R_[6]*y0 + R_[7]*y1 + R_[8]*y2 + t_[2];
        if (p < NPQ) {
            kptsT[((size_t)h * (NPQ*3) + p*3 + 0) * Nres + i] = v0;
            kptsT[((size_t)h * (NPQ*3) + p*3 + 1) * Nres + i] = v1;
            kptsT[((size_t)h * (NPQ*3) + p*3 + 2) * Nres + i] = v2;
            sk += v0*v0 + v1*v1 + v2*v2;
        } else {
            int c0 = 16 + (p - NPQ) * 3;
            vrow[c0 + 0] = v0; vrow[c0 + 1] = v1; vrow[c0 + 2] = v2;
        }
    }
    sqkT[h * Nres + i] = sk;

#pragma unroll
    for (int c = 0; c < HC; c++) {
        kT[((size_t)h * HC + c) * Nres + i] = prow[192 + h * 2 * HC + c];
        vrow[c] = prow[192 + h * 2 * HC + HC + c];
    }
}

// ---------------- attention part 1: logits + softmax + o + o_pt ----------------
// grid (Nres, 3); probs -> attnP; cat written as bf16
__global__ void __launch_bounds__(256)
k_attn_sm(const float* __restrict__ proj, const float* __restrict__ qpts,
          const float* __restrict__ sqq, const float* __restrict__ kT,
          const float* __restrict__ kptsT, const float* __restrict__ sqkT,
          const float* __restrict__ b_hij, const float* __restrict__ hw,
          const float* __restrict__ vh,
          const float* __restrict__ R, const float* __restrict__ t,
          float* __restrict__ attnP, u16* __restrict__ cat_bf) {
    __shared__ float a_sT[512 * 5];
    __shared__ float qs[4 * HC];
    __shared__ float qp[4 * 12];
    __shared__ float sqq_s[4];
    __shared__ float gam[4];
    __shared__ float optg_s[4 * NPV * 3];

    const int i  = blockIdx.x;
    const int hg = blockIdx.y;
    const int tid = threadIdx.x;

    if (tid < 64) qs[tid] = proj[(size_t)i * PROJD + hg * 64 + tid];
    if (tid < 48) qp[tid] = qpts[(size_t)i * 144 + hg * 48 + tid];
    if (tid < 4) {
        sqq_s[tid] = sqq[i * NH + hg * 4 + tid];
        gam[tid] = log1pf(__expf(hw[hg * 4 + tid]));
    }
    __syncthreads();

#pragma unroll
    for (int l = 0; l < 8; l++) {
        int idx = tid + l * 256;
        int h = idx >> 9, j = idx & 511;
        int hglob = hg * 4 + h;
        float sc = 0.f;
#pragma unroll
        for (int c = 0; c < HC; c++) sc += qs[h * 16 + c] * kT[((size_t)hglob * HC + c) * Nres + j];
        sc *= 0.25f;
        float cr = 0.f;
#pragma unroll
        for (int e = 0; e < 12; e++) cr += qp[h * 12 + e] * kptsT[((size_t)hglob * 12 + e) * Nres + j];
        float d2 = sqq_s[h] + sqkT[hglob * Nres + j] - 2.f * cr;
        a_sT[j * 5 + h] = W_L * (sc + b_hij[((size_t)hglob * Nres + i) * Nres + j] - gam[h] * W_C2 * d2);
    }
    __syncthreads();

    {
        int wv = tid >> 6, ln = tid & 63;
        int hglob = hg * 4 + wv;
        float vals[8];
        float m = -1e30f;
#pragma unroll
        for (int jj = 0; jj < 8; jj++) { vals[jj] = a_sT[(ln + jj * 64) * 5 + wv]; m = fmaxf(m, vals[jj]); }
#pragma unroll
        for (int off = 32; off > 0; off >>= 1) m = fmaxf(m, __shfl_xor(m, off));
        float sm = 0.f;
#pragma unroll
        for (int jj = 0; jj < 8; jj++) { vals[jj] = __expf(vals[jj] - m); sm += vals[jj]; }
#pragma unroll
        for (int off = 32; off > 0; off >>= 1) sm += __shfl_xor(sm, off);
        float inv = 1.f / sm;
        float* aP = attnP + ((size_t)i * NH + hglob) * Nres;
#pragma unroll
        for (int jj = 0; jj < 8; jj++) {
            float p = vals[jj] * inv;
            a_sT[(ln + jj * 64) * 5 + wv] = p;
            aP[ln + jj * 64] = p;
        }
    }
    __syncthreads();

    u16* crow = cat_bf + (size_t)i * CATD;

    if (tid < 160) {
        int h = tid / 40;
        int c = tid - h * 40;
        int hglob = hg * 4 + h;
        float acc = 0.f;
        const float* vcol = vh + hglob * 40 + c;
#pragma unroll 8
        for (int j = 0; j < Nres; j++)
            acc += a_sT[j * 5 + h] * vcol[(size_t)j * VHD];
        if (c < 16) crow[hglob * 16 + c] = f2bf(acc);
        else        optg_s[h * 24 + (c - 16)] = acc;
    }
    __syncthreads();

    if (tid < 32) {
        int h = tid >> 3, p = tid & 7;
        int hglob = hg * 4 + h;
        float g0 = optg_s[h * 24 + p * 3 + 0];
        float g1 = optg_s[h * 24 + p * 3 + 1];
        float g2 = optg_s[h * 24 + p * 3 + 2];
        float d0 = g0 - t[i * 3 + 0], d1 = g1 - t[i * 3 + 1], d2v = g2 - t[i * 3 + 2];
        const float* Rn = R + i * 9;
        float l0 = Rn[0] * d0 + Rn[3] * d1 + Rn[6] * d2v;
        float l1 = Rn[1] * d0 + Rn[4] * d1 + Rn[7] * d2v;
        float l2 = Rn[2] * d0 + Rn[5] * d1 + Rn[8] * d2v;
        int hp = hglob * NPV + p;
        crow[192 + hp * 3 + 0] = f2bf(l0);
        crow[192 + hp * 3 + 1] = f2bf(l1);
        crow[192 + hp * 3 + 2] = f2bf(l2);
        crow[480 + hp] = f2bf(sqrtf(l0 * l0 + l1 * l1 + l2 * l2 + 1e-8f));
    }
}

// ---------------- attention part 2: o_pair, one z pass ----------------
__global__ void __launch_bounds__(256)
k_opair(const float* __restrict__ attnP, const float* __restrict__ z,
        float* __restrict__ P2) {
    __shared__ float lds[4608];
    const int i = blockIdx.x, half = blockIdx.y;
    const int tid = threadIdx.x;

#pragma unroll
    for (int l = 0; l < 12; l++) {
        int idx = tid + l * 256;
        int h = idx >> 8, j = idx & 255;
        lds[h * 256 + j] = attnP[((size_t)i * NH + h) * Nres + half * 256 + j];
    }
    __syncthreads();

    const int grp = tid >> 5, zc4 = tid & 31;
    const float4* z4 = (const float4*)(z + ((size_t)i * Nres + half * 256) * Cz);
    float4 accp[NH];
#pragma unroll
    for (int h = 0; h < NH; h++) accp[h] = make_float4(0.f, 0.f, 0.f, 0.f);

#pragma unroll 8
    for (int jj = 0; jj < 32; jj++) {
        int j = grp * 32 + jj;
        float4 zv = z4[j * 32 + zc4];
#pragma unroll
        for (int h = 0; h < NH; h++) {
            float a = lds[h * 256 + j];
            accp[h].x += a * zv.x; accp[h].y += a * zv.y;
            accp[h].z += a * zv.z; accp[h].w += a * zv.w;
        }
    }
    __syncthreads();

#pragma unroll
    for (int h = 0; h < NH; h++) {
        accp[h].x += __shfl_xor(accp[h].x, 32);
        accp[h].y += __shfl_xor(accp[h].y, 32);
        accp[h].z += __shfl_xor(accp[h].z, 32);
        accp[h].w += __shfl_xor(accp[h].w, 32);
    }
    const int wv = tid >> 6, ln = tid & 63;
    float4* red4 = (float4*)lds;
    if (wv >= 1 && ln < 32) {
#pragma unroll
        for (int h = 0; h < NH; h++) red4[(wv - 1) * 384 + h * 32 + ln] = accp[h];
    }
    __syncthreads();
    if (wv == 0 && ln < 32) {
        float4* out4 = (float4*)(P2 + ((size_t)half * Nres + i) * (NH * Cz));
#pragma unroll
        for (int h = 0; h < NH; h++) {
            float4 v = accp[h];
#pragma unroll
            for (int w = 0; w < 3; w++) {
                float4 r = red4[w * 384 + h * 32 + ln];
                v.x += r.x; v.y += r.y; v.z += r.z; v.w += r.w;
            }
            out4[h * 32 + ln] = v;
        }
    }
}

// add the two j-half partials -> bf16 into cat[:, 576:]
__global__ void k_opair_red(const float* __restrict__ P2, u16* __restrict__ cat_bf) {
    int idx = blockIdx.x * blockDim.x + threadIdx.x;
    if (idx >= Nres * NH * Cz) return;
    int i = idx / (NH * Cz), c = idx - i * (NH * Cz);
    float v = P2[(size_t)i * (NH * Cz) + c] + P2[(size_t)(Nres + i) * (NH * Cz) + c];
    cat_bf[(size_t)i * CATD + 576 + c] = f2bf(v);
}

// ---------------- LayerNorm (fp32 in-place + bf16 copy) ----------------
__global__ void k_ln(float* __restrict__ s, u16* __restrict__ s_bf,
                     const float* __restrict__ g, const float* __restrict__ b) {
    __shared__ float red[512];
    int i = blockIdx.x, tid = threadIdx.x;
    float v = s[(size_t)i * Cs + tid];
    red[tid] = v;
    if (tid < 128) red[384 + tid] = 0.f;
    __syncthreads();
    for (int st = 256; st > 0; st >>= 1) { if (tid < st) red[tid] += red[tid + st]; __syncthreads(); }
    float mean = red[0] / Cs;
    __syncthreads();
    float d = v - mean;
    red[tid] = d * d;
    if (tid < 128) red[384 + tid] = 0.f;
    __syncthreads();
    for (int st = 256; st > 0; st >>= 1) { if (tid < st) red[tid] += red[tid + st]; __syncthreads(); }
    float var = red[0] / Cs;
    float o = d * rsqrtf(var + 1e-5f) * g[tid] + b[tid];
    s[(size_t)i * Cs + tid] = o;
    s_bf[(size_t)i * Cs + tid] = f2bf(o);
}

// ---------------- backbone update: one wave per residue ----------------
__global__ void k_bb(const float* __restrict__ s, const float* __restrict__ w_bb,
                     const float* __restrict__ b_bb, float* __restrict__ R, float* __restrict__ t) {
    int wv = threadIdx.x >> 6, lane = threadIdx.x & 63;
    int i = blockIdx.x * 4 + wv;
    const float* sr = s + (size_t)i * Cs;
    float u[6] = {};
#pragma unroll
    for (int k6 = 0; k6 < 6; k6++) {
        int k = lane + k6 * 64;
        float sv = sr[k];
#pragma unroll
        for (int d = 0; d < 6; d++) u[d] += sv * w_bb[k * 6 + d];
    }
#pragma unroll
    for (int off = 32; off > 0; off >>= 1)
#pragma unroll
        for (int d = 0; d < 6; d++) u[d] += __shfl_down(u[d], off);
    if (lane == 0) {
#pragma unroll
        for (int d = 0; d < 6; d++) u[d] += b_bb[d];
        float qb = u[0], qc = u[1], qd = u[2];
        float inv = rsqrtf(1.f + qb*qb + qc*qc + qd*qd);
        float w = inv, x = qb * inv, y = qc * inv, zq = qd * inv;
        float Ru[9] = {
            1.f - 2.f*(y*y + zq*zq), 2.f*(x*y - w*zq),       2.f*(x*zq + w*y),
            2.f*(x*y + w*zq),        1.f - 2.f*(x*x + zq*zq), 2.f*(y*zq - w*x),
            2.f*(x*zq - w*y),        2.f*(y*zq + w*x),        1.f - 2.f*(x*x + y*y)
        };
        float Ro[9];
#pragma unroll
        for (int e = 0; e < 9; e++) Ro[e] = R[i * 9 + e];
        float tu0 = u[3], tu1 = u[4], tu2 = u[5];
        t[i*3+0] += Ro[0]*tu0 + Ro[1]*tu1 + Ro[2]*tu2;
        t[i*3+1] += Ro[3]*tu0 + Ro[4]*tu1 + Ro[5]*tu2;
        t[i*3+2] += Ro[6]*tu0 + Ro[7]*tu1 + Ro[8]*tu2;
#pragma unroll
        for (int r = 0; r < 3; r++)
#pragma unroll
            for (int c = 0; c < 3; c++)
                R[i*9 + r*3 + c] = Ro[r*3+0]*Ru[0*3+c] + Ro[r*3+1]*Ru[1*3+c] + Ro[r*3+2]*Ru[2*3+c];
    }
}

// ---------------- final pack ----------------
__global__ void k_final(const float* __restrict__ s, const float* __restrict__ t,
                        float* __restrict__ out) {
    int idx = blockIdx.x * blockDim.x + threadIdx.x;
    if (idx >= Nres * (Cs + 3)) return;
    int i = idx / (Cs + 3), c = idx - i * (Cs + 3);
    out[idx] = (c < Cs) ? s[(size_t)i * Cs + c] : t[i * 3 + (c - Cs)];
}

// ---------------- launch ----------------
extern "C" void kernel_launch(void* const* d_in, const int* in_sizes, int n_in,
                              void* d_out, int out_size, void* d_ws, size_t ws_size,
                              hipStream_t stream) {
    const float* s_in    = (const float*)d_in[0];
    const float* z       = (const float*)d_in[1];
    const float* w_q     = (const float*)d_in[2];
    const float* w_kv    = (const float*)d_in[3];
    const float* w_qpts  = (const float*)d_in[4];
    const float* w_kvpts = (const float*)d_in[5];
    const float* w_b     = (const float*)d_in[6];
    const float* hw      = (const float*)d_in[7];
    const float* w_out   = (const float*)d_in[8];
    const float* b_out   = (const float*)d_in[9];
    const float* ln1_g   = (const float*)d_in[10];
    const float* ln1_b   = (const float*)d_in[11];
    const float* w_t1    = (const float*)d_in[12];
    const float* w_t2    = (const float*)d_in[13];
    const float* w_t3    = (const float*)d_in[14];
    const float* ln2_g   = (const float*)d_in[15];
    const float* ln2_b   = (const float*)d_in[16];
    const float* w_bb    = (const float*)d_in[17];
    const float* b_bb    = (const float*)d_in[18];
    float* out = (float*)d_out;

    float* ws = (float*)d_ws;
    size_t off = 0;
    float* s_cur = ws + off; off += (size_t)Nres * Cs;
    float* b_hij = ws + off; off += (size_t)NH * Nres * Nres;
    float* proj  = ws + off; off += (size_t)Nres * PROJD;
    float* Wcat  = ws + off; off += (size_t)Cs * PROJD;
    float* qpts  = ws + off; off += (size_t)Nres * NH * NPQ * 3;
    float* sqq   = ws + off; off += (size_t)Nres * NH;
    float* kT    = ws + off; off += (size_t)NH * HC * Nres;
    float* kptsT = ws + off; off += (size_t)NH * NPQ * 3 * Nres;
    float* sqkT  = ws + off; off += (size_t)NH * Nres;
    float* vh    = ws + off; off += (size_t)Nres * VHD;
    float* Rbuf  = ws + off; off += (size_t)Nres * 9;
    float* tbuf  = ws + off; off += (size_t)Nres * 3;
    float* Pslab = ws + off; off += (size_t)11 * Nres * Cs;
    float* attnP = ws + off; off += (size_t)Nres * NH * Nres;
    float* P2    = ws + off; off += (size_t)2 * Nres * NH * Cz;
    // bf16 buffers (carved in float units, halved counts)
    u16* s_bf   = (u16*)(ws + off); off += (size_t)Nres * Cs / 2;
    u16* cat_bf = (u16*)(ws + off); off += (size_t)Nres * CATD / 2;
    u16* h1_bf  = (u16*)(ws + off); off += (size_t)Nres * Cs / 2;
    u16* h2_bf  = (u16*)(ws + off); off += (size_t)Nres * Cs / 2;
    u16* WcatT  = (u16*)(ws + off); off += (size_t)Cs * PROJD / 2;
    u16* w_outT = (u16*)(ws + off); off += (size_t)CATD * Cs / 2;
    u16* w_t1T  = (u16*)(ws + off); off += (size_t)Cs * Cs / 2;
    u16* w_t2T  = (u16*)(ws + off); off += (size_t)Cs * Cs / 2;
    u16* w_t3T  = (u16*)(ws + off); off += (size_t)Cs * Cs / 2;

    const int MNp = Nres * PROJD;
    const int MNs = Nres * Cs;

    k_init<<<gdiv(Nres*Cs, 256), 256, 0, stream>>>(s_in, s_cur, s_bf, Rbuf, tbuf);
    k_concatW<<<gdiv(Cs*PROJD, 256), 256, 0, stream>>>(w_q, w_kv, w_qpts, w_kvpts, Wcat);
    k_transposeW<<<dim3(PROJD/32, Cs/32), 256, 0, stream>>>(Wcat, WcatT, Cs, PROJD);
    k_transposeW<<<dim3(Cs/32, CATD/32), 256, 0, stream>>>(w_out, w_outT, CATD, Cs);
    k_transposeW<<<dim3(Cs/32, Cs/32), 256, 0, stream>>>(w_t1, w_t1T, Cs, Cs);
    k_transposeW<<<dim3(Cs/32, Cs/32), 256, 0, stream>>>(w_t2, w_t2T, Cs, Cs);
    k_transposeW<<<dim3(Cs/32, Cs/32), 256, 0, stream>>>(w_t3, w_t3T, Cs, Cs);
    k_bproj<<<Nres*Nres/16, 256, 0, stream>>>(z, w_b, b_hij);

    for (int it = 0; it < NBLK; it++) {
        // proj = s @ Wcat  (512 x 384 x 1152), split-K=2, MFMA
        k_gemm_mfma<<<dim3(PROJD/64, Nres/64, 2), 256, 0, stream>>>(s_bf, WcatT, Pslab, Nres, Cs, PROJD, 192);
        k_reduce<<<gdiv(MNp, 256), 256, 0, stream>>>(Pslab, nullptr, proj, MNp, PROJD, 2, 0);
        // point transforms + staging
        k_prep<<<gdiv(NH*Nres, 256), 256, 0, stream>>>(proj, Rbuf, tbuf, qpts, sqq, kT, kptsT, sqkT, vh);
        // attention
        k_attn_sm<<<dim3(Nres, 3), 256, 0, stream>>>(proj, qpts, sqq, kT, kptsT, sqkT, b_hij, hw, vh, Rbuf, tbuf, attnP, cat_bf);
        k_opair<<<dim3(Nres, 2), 256, 0, stream>>>(attnP, z, P2);
        k_opair_red<<<gdiv(Nres*NH*Cz, 256), 256, 0, stream>>>(P2, cat_bf);
        // s += cat @ w_out + b_out  (512 x 2112 x 384), split-K=11, MFMA
        k_gemm_mfma<<<dim3(Cs/64, Nres/64, 11), 256, 0, stream>>>(cat_bf, w_outT, Pslab, Nres, CATD, Cs, 192);
        k_reduce<<<gdiv(MNs, 256), 256, 0, stream>>>(Pslab, b_out, s_cur, MNs, Cs, 11, 2);
        k_ln<<<Nres, Cs, 0, stream>>>(s_cur, s_bf, ln1_g, ln1_b);
        // transition (512 x 384 x 384), split-K=6, MFMA
        k_gemm_mfma<<<dim3(Cs/64, Nres/64, 6), 256, 0, stream>>>(s_bf, w_t1T, Pslab, Nres, Cs, Cs, 64);
        k_reduce_relu_bf<<<gdiv(MNs, 256), 256, 0, stream>>>(Pslab, h1_bf, MNs, 6);
        k_gemm_mfma<<<dim3(Cs/64, Nres/64, 6), 256, 0, stream>>>(h1_bf, w_t2T, Pslab, Nres, Cs, Cs, 64);
        k_reduce_relu_bf<<<gdiv(MNs, 256), 256, 0, stream>>>(Pslab, h2_bf, MNs, 6);
        k_gemm_mfma<<<dim3(Cs/64, Nres/64, 6), 256, 0, stream>>>(h2_bf, w_t3T, Pslab, Nres, Cs, Cs, 64);
        k_reduce<<<gdiv(MNs, 256), 256, 0, stream>>>(Pslab, nullptr, s_cur, MNs, Cs, 6, 2);
        k_ln<<<Nres, Cs, 0, stream>>>(s_cur, s_bf, ln2_g, ln2_b);
        // backbone update
        k_bb<<<Nres/4, 256, 0, stream>>>(s_cur, w_bb, b_bb, Rbuf, tbuf);
    }

    k_final<<<gdiv(Nres*(Cs+3), 256), 256, 0, stream>>>(s_cur, tbuf, out);
}